// Round 3
// baseline (3286.528 us; speedup 1.0000x reference)
//
#include <hip/hip_runtime.h>
#include <hip/hip_bf16.h>

typedef __hip_bfloat16 bf16;

#define NN 32768
#define NE 524288
#define D 128
#define H 4
#define C 32
#define R 5
#define BS 8192

__device__ __forceinline__ float b2f(bf16 x) { return __bfloat162float(x); }
__device__ __forceinline__ bf16 f2b(float x) { return __float2bfloat16(x); }
__device__ __forceinline__ float gelu_f(float x) {
    return 0.5f * x * (1.f + erff(x * 0.7071067811865475f));
}
// monotonic float<->uint encoding for atomicMax-based segment max
__device__ __forceinline__ unsigned enc_max(float a) {
    unsigned u = __float_as_uint(a);
    return (u & 0x80000000u) ? ~u : (u | 0x80000000u);
}
__device__ __forceinline__ float dec_max(unsigned u) {
    if (u == 0u) return 0.f;   // untouched slot guard (never read in practice)
    unsigned bits = (u & 0x80000000u) ? (u ^ 0x80000000u) : ~u;
    return __uint_as_float(bits);
}

// ---- static device scratch (size-guaranteed, graph-capture safe) ----
__device__ float    g_x[NN * D];       // f32 working activations
__device__ float    g_acc[NN * D];     // aggregation accumulator
__device__ unsigned g_nmax[NN * H];    // encoded per-(dst,head) max
__device__ float    g_den[NN * H];     // softmax denominator
__device__ float    g_araw[NE * H];    // raw attention logits
__device__ float    g_P[R * NN * D];   // x @ Rtop[r]
__device__ float    g_Q[R * NN * D];   // x @ Rbot[r]
__device__ float    g_xl[NN * D];      // x @ Wl + bl

// ---- copy f32 embeddings to working buffer ----
__global__ void k_cvt(const float* __restrict__ e) {
    int i = blockIdx.x * 256 + threadIdx.x;
    g_x[i] = e[i];
}

// ---- zero acc / nmax / den ----
__global__ void k_zero() {
    int i = blockIdx.x * 256 + threadIdx.x;   // NN*D threads
    g_acc[i] = 0.f;
    if (i < NN * H) { g_nmax[i] = 0u; g_den[i] = 0.f; }
}

// ---- node transforms: xl = x@Wl + bl ; P[r] = x@Rtop[r] ; Q[r] = x@Rbot[r] ----
// grid: (NN/32, 2R+1), block: 128
__global__ void k_node(const float* __restrict__ Wl, const float* __restrict__ bl,
                       const float* __restrict__ Rm) {
    __shared__ __align__(16) float xs[32][D];
    const int col = threadIdx.x;
    const int n0 = blockIdx.x * 32;
    const int w = blockIdx.y;
    for (int rr = 0; rr < 32; ++rr) xs[rr][col] = g_x[(size_t)(n0 + rr) * D + col];
    __syncthreads();

    const float* W;
    float* out;
    float bias = 0.f;
    if (w == 0) { W = Wl; out = g_xl; bias = bl[col]; }
    else if (w <= R) { int r = w - 1; W = Rm + (size_t)r * 2 * D * D; out = g_P + (size_t)r * NN * D; }
    else { int r = w - 1 - R; W = Rm + (size_t)r * 2 * D * D + D * D; out = g_Q + (size_t)r * NN * D; }

    float acc[32];
#pragma unroll
    for (int i = 0; i < 32; ++i) acc[i] = 0.f;

    for (int k = 0; k < D; k += 4) {
        float w0 = W[(k + 0) * D + col];
        float w1 = W[(k + 1) * D + col];
        float w2 = W[(k + 2) * D + col];
        float w3 = W[(k + 3) * D + col];
#pragma unroll
        for (int i = 0; i < 32; ++i) {
            const float4 xv = *(const float4*)&xs[i][k];
            acc[i] = fmaf(xv.w, w3, fmaf(xv.z, w2, fmaf(xv.y, w1, fmaf(xv.x, w0, acc[i]))));
        }
    }
    for (int i = 0; i < 32; ++i)
        out[(size_t)(n0 + i) * D + col] = acc[i] + bias;
}

// ---- fused edge kernel: ea = gelu(P[et][src]+Q[et][dst]); m = xl[src]+xl[dst]+ea@We;
//      alpha_raw = einsum(leakyrelu(m), att); atomicMax per (dst, head) ----
// grid: NE/16, block: 256
__global__ __launch_bounds__(256) void k_edge(
        const float* __restrict__ We, const float* __restrict__ att,
        const int* __restrict__ ei, const int* __restrict__ et) {
    __shared__ __align__(16) bf16 sWe[D * D];   // 32 KB (bf16 to stay under 64 KB/block)
    __shared__ __align__(16) float ea[16][D];   // 8 KB
    __shared__ float als[16][H];
    __shared__ int es[16], ed[16], er[16];
    const int tid = threadIdx.x;
    const int e0 = blockIdx.x * 16;

    for (int i = tid; i < D * D; i += 256) sWe[i] = f2b(We[i]);
    if (tid < 16) {
        es[tid] = ei[e0 + tid];
        ed[tid] = ei[NE + e0 + tid];
        er[tid] = et[e0 + tid];
    }
    __syncthreads();

    // ea tile
#pragma unroll
    for (int it = 0; it < 8; ++it) {
        int p = it * 256 + tid;
        int i = p >> 7, j = p & 127;
        size_t ps = ((size_t)er[i] * NN + es[i]) * D + j;
        size_t qs = ((size_t)er[i] * NN + ed[i]) * D + j;
        ea[i][j] = gelu_f(g_P[ps] + g_Q[qs]);
    }
    __syncthreads();

    // m + per-head attention logit
#pragma unroll 1
    for (int it = 0; it < 8; ++it) {
        int p = it * 256 + tid;
        int i = p >> 7, j = p & 127;
        float m = g_xl[(size_t)es[i] * D + j] + g_xl[(size_t)ed[i] * D + j];
        const float* eav = ea[i];
#pragma unroll 8
        for (int k = 0; k < D; ++k) m = fmaf(eav[k], b2f(sWe[k * D + j]), m);
        float lr = m > 0.f ? m : 0.2f * m;
        int h = j >> 5;
        float t = lr * att[h * C + (j & 31)];
        t += __shfl_xor(t, 16); t += __shfl_xor(t, 8); t += __shfl_xor(t, 4);
        t += __shfl_xor(t, 2);  t += __shfl_xor(t, 1);
        if ((j & 31) == 0) als[i][h] = t;
    }
    __syncthreads();

    if (tid < 64) {
        int i = tid >> 2, h = tid & 3;
        float a = als[i][h];
        g_araw[(size_t)(e0 + i) * H + h] = a;
        atomicMax(&g_nmax[(size_t)ed[i] * H + h], enc_max(a));
    }
}

// ---- denom pass ----
__global__ void k_denom(const int* __restrict__ ei) {
    int idx = blockIdx.x * 256 + threadIdx.x;   // NE*H total
    int e = idx >> 2, h = idx & 3;
    int d = ei[NE + e];
    float mx = dec_max(g_nmax[(size_t)d * H + h]);
    atomicAdd(&g_den[(size_t)d * H + h], __expf(g_araw[idx] - mx));
}

// ---- aggregation: acc[dst] += xl[src] * alpha ----
// grid: NE/2, block 256 (2 edges x 128 cols)
__global__ void k_aggr(const int* __restrict__ ei) {
    int tid = threadIdx.x;
    int e = blockIdx.x * 2 + (tid >> 7);
    int j = tid & 127;
    int s = ei[e], d = ei[NE + e];
    int h = j >> 5;
    float mx = dec_max(g_nmax[(size_t)d * H + h]);
    float a = __expf(g_araw[(size_t)e * H + h] - mx);
    float cf = a / (g_den[(size_t)d * H + h] + 1e-16f);
    float v = g_xl[(size_t)s * D + j] * cf;
    atomicAdd(&g_acc[(size_t)d * D + j], v);
}

// ---- finalize: x = act(acc + bias) ----
__global__ void k_fin(const float* __restrict__ bias, int do_gelu) {
    int idx = blockIdx.x * 256 + threadIdx.x;
    float v = g_acc[idx] + bias[idx & 127];
    g_x[idx] = do_gelu ? gelu_f(v) : v;
}

// ---- output head: y = x[:BS]@out_w + out_b ; LayerNorm(eps=1e-12) ----
// grid: BS, block: 128
__global__ void k_head(const float* __restrict__ ow, const float* __restrict__ ob,
                       const float* __restrict__ g, const float* __restrict__ b,
                       float* __restrict__ out) {
    __shared__ float xs[D];
    __shared__ float red[D];
    int j = threadIdx.x, row = blockIdx.x;
    xs[j] = g_x[(size_t)row * D + j];
    __syncthreads();
    float y = ob[j];
#pragma unroll 8
    for (int k = 0; k < D; ++k) y = fmaf(xs[k], ow[k * D + j], y);
    red[j] = y;
    __syncthreads();
    for (int s = 64; s > 0; s >>= 1) { if (j < s) red[j] += red[j + s]; __syncthreads(); }
    float mu = red[0] * (1.f / D);
    __syncthreads();
    float dv = y - mu;
    red[j] = dv * dv;
    __syncthreads();
    for (int s = 64; s > 0; s >>= 1) { if (j < s) red[j] += red[j + s]; __syncthreads(); }
    float var = red[0] * (1.f / D);
    out[(size_t)row * D + j] = dv * rsqrtf(var + 1e-12f) * g[j] + b[j];
}

extern "C" void kernel_launch(void* const* d_in, const int* in_sizes, int n_in,
                              void* d_out, int out_size, void* d_ws, size_t ws_size,
                              hipStream_t stream) {
    (void)in_sizes; (void)n_in; (void)out_size; (void)d_ws; (void)ws_size;
    const float* embs = (const float*)d_in[0];
    const int*   ei   = (const int*)d_in[1];
    const int*   et   = (const int*)d_in[2];
    const float* rel  = (const float*)d_in[3];
    const float* wl[2]   = { (const float*)d_in[4],  (const float*)d_in[9]  };
    const float* bl[2]   = { (const float*)d_in[5],  (const float*)d_in[10] };
    const float* we[2]   = { (const float*)d_in[6],  (const float*)d_in[11] };
    const float* attw[2] = { (const float*)d_in[7],  (const float*)d_in[12] };
    const float* bs[2]   = { (const float*)d_in[8],  (const float*)d_in[13] };
    const float* ow  = (const float*)d_in[14];
    const float* ob  = (const float*)d_in[15];
    const float* lng = (const float*)d_in[16];
    const float* lnb = (const float*)d_in[17];
    float* out = (float*)d_out;

    k_cvt<<<NN * D / 256, 256, 0, stream>>>(embs);

    for (int l = 0; l < 2; ++l) {
        const float* Rm = rel + (size_t)l * R * 2 * D * D;
        k_node<<<dim3(NN / 32, 2 * R + 1), 128, 0, stream>>>(wl[l], bl[l], Rm);
        k_zero<<<NN * D / 256, 256, 0, stream>>>();
        k_edge<<<NE / 16, 256, 0, stream>>>(we[l], attw[l], ei, et);
        k_denom<<<NE * H / 256, 256, 0, stream>>>(ei);
        k_aggr<<<NE / 2, 256, 0, stream>>>(ei);
        k_fin<<<NN * D / 256, 256, 0, stream>>>(bs[l], l == 0 ? 1 : 0);
    }

    k_head<<<BS, 128, 0, stream>>>(ow, ob, lng, lnb, out);
}

// Round 4
// 1707.686 us; speedup vs baseline: 1.9246x; 1.9246x over previous
//
#include <hip/hip_runtime.h>
#include <hip/hip_bf16.h>

typedef __hip_bfloat16 bf16;
typedef __attribute__((ext_vector_type(8))) short s8v;
typedef __attribute__((ext_vector_type(4))) float f4v;
typedef unsigned short u16;
typedef unsigned int u32;

#define NN 32768
#define NE 524288
#define D 128
#define H 4
#define C 32
#define R 5
#define BS 8192
#define LW 136   // padded LDS row stride (bf16 elems): 68 words -> conflict-free

__device__ __forceinline__ float b2f(bf16 x) { return __bfloat162float(x); }
__device__ __forceinline__ bf16 f2b(float x) { return __float2bfloat16(x); }
__device__ __forceinline__ u16 f2bs(float x) { bf16 h = f2b(x); return *(u16*)&h; }
__device__ __forceinline__ float us2f(u16 u) { return __uint_as_float(((u32)u) << 16); }
__device__ __forceinline__ float bflo(u32 u) { return __uint_as_float(u << 16); }
__device__ __forceinline__ float bfhi(u32 u) { return __uint_as_float(u & 0xffff0000u); }
__device__ __forceinline__ u32 pack2(float a, float b) {
    return (u32)f2bs(a) | ((u32)f2bs(b) << 16);
}
__device__ __forceinline__ float gelu_f(float x) {
    return 0.5f * x * (1.f + erff(x * 0.7071067811865475f));
}
__device__ __forceinline__ unsigned enc_max(float a) {
    unsigned u = __float_as_uint(a);
    return (u & 0x80000000u) ? ~u : (u | 0x80000000u);
}
__device__ __forceinline__ float dec_max(unsigned u) {
    if (u == 0u) return 0.f;
    unsigned bits = (u & 0x80000000u) ? (u ^ 0x80000000u) : ~u;
    return __uint_as_float(bits);
}

// ---- static device scratch ----
__device__ float    g_x[NN * D];       // f32 working activations
__device__ float    g_acc[NN * D];     // aggregation accumulator
__device__ unsigned g_nmax[NN * H];    // encoded per-(dst,head) max
__device__ float    g_den[NN * H];     // softmax denominator
__device__ float    g_araw[NE * H];    // raw attention logits
__device__ u16      g_P[R * NN * D];   // bf16: x @ Rtop[r]
__device__ u16      g_Q[R * NN * D];   // bf16: x @ Rbot[r]
__device__ u16      g_xl[NN * D];      // bf16: x @ Wl + bl
__device__ u16      g_WeT[D * D];      // bf16: We transposed [n][k]

__global__ void k_cvt(const float* __restrict__ e) {
    int i = blockIdx.x * 256 + threadIdx.x;
    g_x[i] = e[i];
}

__global__ void k_zero() {
    int i = blockIdx.x * 256 + threadIdx.x;   // NN*D threads
    g_acc[i] = 0.f;
    if (i < NN * H) { g_nmax[i] = 0u; g_den[i] = 0.f; }
}

// ---- transpose + bf16-cast We: g_WeT[n][k] = We[k][n] ----
__global__ void k_prep(const float* __restrict__ We) {
    int i = blockIdx.x * 256 + threadIdx.x;   // D*D
    int k = i >> 7, n = i & 127;
    g_WeT[n * D + k] = f2bs(We[i]);
}

// ---- node transforms: xl = x@Wl + bl ; P[r] = x@Rtop[r] ; Q[r] = x@Rbot[r] ----
// grid: (NN/32, 2R+1), block: 128  — outputs bf16
__global__ void k_node(const float* __restrict__ Wl, const float* __restrict__ bl,
                       const float* __restrict__ Rm) {
    __shared__ __align__(16) float xs[32][D];
    const int col = threadIdx.x;
    const int n0 = blockIdx.x * 32;
    const int w = blockIdx.y;
    for (int rr = 0; rr < 32; ++rr) xs[rr][col] = g_x[(size_t)(n0 + rr) * D + col];
    __syncthreads();

    const float* W;
    u16* out;
    float bias = 0.f;
    if (w == 0) { W = Wl; out = g_xl; bias = bl[col]; }
    else if (w <= R) { int r = w - 1; W = Rm + (size_t)r * 2 * D * D; out = g_P + (size_t)r * NN * D; }
    else { int r = w - 1 - R; W = Rm + (size_t)r * 2 * D * D + D * D; out = g_Q + (size_t)r * NN * D; }

    float acc[32];
#pragma unroll
    for (int i = 0; i < 32; ++i) acc[i] = 0.f;

    for (int k = 0; k < D; k += 4) {
        float w0 = W[(k + 0) * D + col];
        float w1 = W[(k + 1) * D + col];
        float w2 = W[(k + 2) * D + col];
        float w3 = W[(k + 3) * D + col];
#pragma unroll
        for (int i = 0; i < 32; ++i) {
            const float4 xv = *(const float4*)&xs[i][k];
            acc[i] = fmaf(xv.w, w3, fmaf(xv.z, w2, fmaf(xv.y, w1, fmaf(xv.x, w0, acc[i]))));
        }
    }
    for (int i = 0; i < 32; ++i)
        out[(size_t)(n0 + i) * D + col] = f2bs(acc[i] + bias);
}

// ---- fused edge kernel (MFMA): 64 edges/block, 4 waves x 16-edge M-tiles ----
// m[64x128] = gelu(P[src]+Q[dst]) @ We + xl[src] + xl[dst]; logits + atomicMax
__global__ __launch_bounds__(256) void k_edge(
        const float* __restrict__ att, const int* __restrict__ ei,
        const int* __restrict__ et) {
    __shared__ __align__(16) short sWeT[D * LW];   // 34816 B
    __shared__ __align__(16) short sEa[64 * LW];   // 17408 B
    __shared__ float als[64][H];
    __shared__ int es[64], ed[64], er[64];
    const int tid = threadIdx.x;
    const int e0 = blockIdx.x * 64;

    if (tid < 64) {
        es[tid] = ei[e0 + tid];
        ed[tid] = ei[NE + e0 + tid];
        er[tid] = et[e0 + tid];
    }
    // stage WeT (coalesced uint4 -> ds_write_b128), 8 iters
#pragma unroll
    for (int i = 0; i < 8; ++i) {
        int flat = i * 256 + tid;          // 2048 chunks of 8 bf16
        int n = flat >> 4, c8 = (flat & 15) << 3;
        *(uint4*)&sWeT[n * LW + c8] = *(const uint4*)&g_WeT[n * D + c8];
    }
    __syncthreads();

    // ea = gelu(P+Q), bf16, 2 cols per iter
#pragma unroll
    for (int i = 0; i < 16; ++i) {
        int flat = i * 256 + tid;          // 4096 col-pairs
        int row = flat >> 6;
        int cp = (flat & 63) << 1;
        size_t pb = ((size_t)er[row] * NN + es[row]) * D + cp;
        size_t qb = ((size_t)er[row] * NN + ed[row]) * D + cp;
        u32 pu = *(const u32*)&g_P[pb];
        u32 qu = *(const u32*)&g_Q[qb];
        float v0 = gelu_f(bflo(pu) + bflo(qu));
        float v1 = gelu_f(bfhi(pu) + bfhi(qu));
        ((u32*)sEa)[row * (LW / 2) + (cp >> 1)] = pack2(v0, v1);
    }
    __syncthreads();

    // MFMA: wave w computes edges w*16..w*16+15, all 128 cols
    const int l = tid & 63, w = tid >> 6;
    const int mrow = l & 15, quad = l >> 4;
    f4v acc[8];
#pragma unroll
    for (int nt = 0; nt < 8; ++nt) acc[nt] = (f4v){0.f, 0.f, 0.f, 0.f};
#pragma unroll
    for (int s = 0; s < 4; ++s) {
        s8v a = *(const s8v*)&sEa[(w * 16 + mrow) * LW + s * 32 + quad * 8];
#pragma unroll
        for (int nt = 0; nt < 8; ++nt) {
            s8v b = *(const s8v*)&sWeT[(nt * 16 + mrow) * LW + s * 32 + quad * 8];
            acc[nt] = __builtin_amdgcn_mfma_f32_16x16x32_bf16(a, b, acc[nt], 0, 0, 0);
        }
    }

    // epilogue in C-layout: row(edge)=quad*4+r, col=nt*16+mrow
    float hsum[4][4];
#pragma unroll
    for (int r = 0; r < 4; ++r)
#pragma unroll
        for (int h = 0; h < 4; ++h) hsum[r][h] = 0.f;
#pragma unroll
    for (int nt = 0; nt < 8; ++nt) {
        int col = nt * 16 + mrow;
        float av = att[col];
        int h = nt >> 1;
#pragma unroll
        for (int r = 0; r < 4; ++r) {
            int el = w * 16 + quad * 4 + r;
            float m = acc[nt][r]
                    + us2f(g_xl[(size_t)es[el] * D + col])
                    + us2f(g_xl[(size_t)ed[el] * D + col]);
            float lr = m > 0.f ? m : 0.2f * m;
            hsum[r][h] = fmaf(lr, av, hsum[r][h]);
        }
    }
#pragma unroll
    for (int r = 0; r < 4; ++r)
#pragma unroll
        for (int h = 0; h < 4; ++h) {
            float v = hsum[r][h];
            v += __shfl_xor(v, 1); v += __shfl_xor(v, 2);
            v += __shfl_xor(v, 4); v += __shfl_xor(v, 8);
            hsum[r][h] = v;
        }
    if (mrow == 0) {
#pragma unroll
        for (int r = 0; r < 4; ++r)
#pragma unroll
            for (int h = 0; h < 4; ++h)
                als[w * 16 + quad * 4 + r][h] = hsum[r][h];
    }
    __syncthreads();

    {   // 64 edges x 4 heads = 256 threads
        int el = tid >> 2, h = tid & 3;
        float a = als[el][h];
        g_araw[(size_t)(e0 + el) * H + h] = a;
        atomicMax(&g_nmax[(size_t)ed[el] * H + h], enc_max(a));
    }
}

// ---- denom pass ----
__global__ void k_denom(const int* __restrict__ ei) {
    int idx = blockIdx.x * 256 + threadIdx.x;   // NE*H total
    int e = idx >> 2, h = idx & 3;
    int d = ei[NE + e];
    float mx = dec_max(g_nmax[(size_t)d * H + h]);
    atomicAdd(&g_den[(size_t)d * H + h], __expf(g_araw[idx] - mx));
}

// ---- aggregation: acc[dst] += xl[src] * alpha ----
__global__ void k_aggr(const int* __restrict__ ei) {
    int tid = threadIdx.x;
    int e = blockIdx.x * 2 + (tid >> 7);
    int j = tid & 127;
    int s = ei[e], d = ei[NE + e];
    int h = j >> 5;
    float mx = dec_max(g_nmax[(size_t)d * H + h]);
    float a = __expf(g_araw[(size_t)e * H + h] - mx);
    float cf = a / (g_den[(size_t)d * H + h] + 1e-16f);
    float v = us2f(g_xl[(size_t)s * D + j]) * cf;
    atomicAdd(&g_acc[(size_t)d * D + j], v);
}

// ---- finalize: x = act(acc + bias) ----
__global__ void k_fin(const float* __restrict__ bias, int do_gelu) {
    int idx = blockIdx.x * 256 + threadIdx.x;
    float v = g_acc[idx] + bias[idx & 127];
    g_x[idx] = do_gelu ? gelu_f(v) : v;
}

// ---- output head: y = x[:BS]@out_w + out_b ; LayerNorm(eps=1e-12) ----
__global__ void k_head(const float* __restrict__ ow, const float* __restrict__ ob,
                       const float* __restrict__ g, const float* __restrict__ b,
                       float* __restrict__ out) {
    __shared__ float xs[D];
    __shared__ float red[D];
    int j = threadIdx.x, row = blockIdx.x;
    xs[j] = g_x[(size_t)row * D + j];
    __syncthreads();
    float y = ob[j];
#pragma unroll 8
    for (int k = 0; k < D; ++k) y = fmaf(xs[k], ow[k * D + j], y);
    red[j] = y;
    __syncthreads();
    for (int s = 64; s > 0; s >>= 1) { if (j < s) red[j] += red[j + s]; __syncthreads(); }
    float mu = red[0] * (1.f / D);
    __syncthreads();
    float dv = y - mu;
    red[j] = dv * dv;
    __syncthreads();
    for (int s = 64; s > 0; s >>= 1) { if (j < s) red[j] += red[j + s]; __syncthreads(); }
    float var = red[0] * (1.f / D);
    out[(size_t)row * D + j] = dv * rsqrtf(var + 1e-12f) * g[j] + b[j];
}

extern "C" void kernel_launch(void* const* d_in, const int* in_sizes, int n_in,
                              void* d_out, int out_size, void* d_ws, size_t ws_size,
                              hipStream_t stream) {
    (void)in_sizes; (void)n_in; (void)out_size; (void)d_ws; (void)ws_size;
    const float* embs = (const float*)d_in[0];
    const int*   ei   = (const int*)d_in[1];
    const int*   et   = (const int*)d_in[2];
    const float* rel  = (const float*)d_in[3];
    const float* wl[2]   = { (const float*)d_in[4],  (const float*)d_in[9]  };
    const float* bl[2]   = { (const float*)d_in[5],  (const float*)d_in[10] };
    const float* we[2]   = { (const float*)d_in[6],  (const float*)d_in[11] };
    const float* attw[2] = { (const float*)d_in[7],  (const float*)d_in[12] };
    const float* bs[2]   = { (const float*)d_in[8],  (const float*)d_in[13] };
    const float* ow  = (const float*)d_in[14];
    const float* ob  = (const float*)d_in[15];
    const float* lng = (const float*)d_in[16];
    const float* lnb = (const float*)d_in[17];
    float* out = (float*)d_out;

    k_cvt<<<NN * D / 256, 256, 0, stream>>>(embs);

    for (int l = 0; l < 2; ++l) {
        const float* Rm = rel + (size_t)l * R * 2 * D * D;
        k_node<<<dim3(NN / 32, 2 * R + 1), 128, 0, stream>>>(wl[l], bl[l], Rm);
        k_prep<<<D * D / 256, 256, 0, stream>>>(we[l]);
        k_zero<<<NN * D / 256, 256, 0, stream>>>();
        k_edge<<<NE / 64, 256, 0, stream>>>(attw[l], ei, et);
        k_denom<<<NE * H / 256, 256, 0, stream>>>(ei);
        k_aggr<<<NE / 2, 256, 0, stream>>>(ei);
        k_fin<<<NN * D / 256, 256, 0, stream>>>(bs[l], l == 0 ? 1 : 0);
    }

    k_head<<<BS, 128, 0, stream>>>(ow, ob, lng, lnb, out);
}

// Round 5
// 1310.368 us; speedup vs baseline: 2.5081x; 1.3032x over previous
//
#include <hip/hip_runtime.h>
#include <hip/hip_bf16.h>

typedef __hip_bfloat16 bf16;
typedef __attribute__((ext_vector_type(8))) short s8v;
typedef __attribute__((ext_vector_type(4))) float f4v;
typedef unsigned short u16;
typedef unsigned int u32;

#define NN 32768
#define NE 524288
#define D 128
#define H 4
#define C 32
#define R 5
#define BS 8192
#define LW 136   // padded LDS row stride (bf16 elems): 68 words -> conflict-free

__device__ __forceinline__ float b2f(bf16 x) { return __bfloat162float(x); }
__device__ __forceinline__ bf16 f2b(float x) { return __float2bfloat16(x); }
__device__ __forceinline__ u16 f2bs(float x) { bf16 h = f2b(x); return *(u16*)&h; }
__device__ __forceinline__ float us2f(u16 u) { return __uint_as_float(((u32)u) << 16); }
__device__ __forceinline__ float bflo(u32 u) { return __uint_as_float(u << 16); }
__device__ __forceinline__ float bfhi(u32 u) { return __uint_as_float(u & 0xffff0000u); }
__device__ __forceinline__ u32 pack2(float a, float b) {
    return (u32)f2bs(a) | ((u32)f2bs(b) << 16);
}
__device__ __forceinline__ float gelu_f(float x) {
    return 0.5f * x * (1.f + erff(x * 0.7071067811865475f));
}
__device__ __forceinline__ unsigned enc_max(float a) {
    unsigned u = __float_as_uint(a);
    return (u & 0x80000000u) ? ~u : (u | 0x80000000u);
}
__device__ __forceinline__ float dec_max(unsigned u) {
    if (u == 0u) return 0.f;
    unsigned bits = (u & 0x80000000u) ? (u ^ 0x80000000u) : ~u;
    return __uint_as_float(bits);
}

// ---- static device scratch ----
__device__ float    g_x[NN * D];        // f32 working activations
__device__ float    g_acc[NN * D];      // aggregation accumulator
__device__ unsigned g_nmax[NN * H];     // encoded per-(dst,head) max
__device__ float    g_den[NN * H];      // softmax denominator
__device__ float    g_araw[NE * H];     // raw attention logits
__device__ u16      g_P[R * NN * D];    // bf16: x @ Rtop[r]
__device__ u16      g_Q[R * NN * D];    // bf16: x @ Rbot[r]
__device__ u16      g_xl[NN * D];       // bf16: x @ Wl + bl
__device__ u16      g_Wn[12 * D * D];   // bf16 transposed weights: Wl,Rtop[5],Rbot[5],We

__global__ void k_cvt(const float* __restrict__ e) {
    int i = blockIdx.x * 256 + threadIdx.x;
    g_x[i] = e[i];
}

__global__ void k_zero() {
    int i = blockIdx.x * 256 + threadIdx.x;   // NN*D threads
    g_acc[i] = 0.f;
    if (i < NN * H) { g_nmax[i] = 0u; g_den[i] = 0.f; }
}

// ---- transpose + bf16-cast all 12 weight matrices: Wt[n][k] = W[k][n] ----
// grid: (D*D/256, 12)
__global__ void k_prep(const float* __restrict__ Wl, const float* __restrict__ Rm,
                       const float* __restrict__ We) {
    int i = blockIdx.x * 256 + threadIdx.x;   // source element
    int y = blockIdx.y;
    int k = i >> 7, n = i & 127;
    const float* src;
    if (y == 0) src = Wl;
    else if (y <= R) src = Rm + (size_t)(y - 1) * 2 * D * D;
    else if (y <= 2 * R) src = Rm + (size_t)(y - 1 - R) * 2 * D * D + D * D;
    else src = We;
    g_Wn[(size_t)y * D * D + n * D + k] = f2bs(src[i]);
}

// ---- node transforms (MFMA): xl / P[r] / Q[r] = x @ W (+ bias for xl) ----
// grid: (NN/64, 11), block 256 (4 waves x 16-node tiles)
__global__ __launch_bounds__(256) void k_node(const float* __restrict__ bl) {
    __shared__ __align__(16) short sX[64 * LW];   // 17408 B
    __shared__ __align__(16) short sW[D * LW];    // 34816 B
    const int tid = threadIdx.x;
    const int n0 = blockIdx.x * 64;
    const int wsel = blockIdx.y;

    // stage x-tile f32 -> bf16
#pragma unroll
    for (int i = 0; i < 16; ++i) {
        int flat = i * 256 + tid;          // 4096 col-pairs
        int row = flat >> 6, cp = (flat & 63) << 1;
        const float2 v = *(const float2*)&g_x[(size_t)(n0 + row) * D + cp];
        ((u32*)sX)[row * (LW / 2) + (cp >> 1)] = pack2(v.x, v.y);
    }
    // stage weight (pre-transposed bf16)
    const u16* Wt = g_Wn + (size_t)wsel * D * D;
#pragma unroll
    for (int i = 0; i < 8; ++i) {
        int flat = i * 256 + tid;          // 2048 chunks of 8 bf16
        int n = flat >> 4, c8 = (flat & 15) << 3;
        *(uint4*)&sW[n * LW + c8] = *(const uint4*)&Wt[n * D + c8];
    }
    __syncthreads();

    const int l = tid & 63, w = tid >> 6;
    const int mrow = l & 15, quad = l >> 4;
    f4v acc[8];
#pragma unroll
    for (int nt = 0; nt < 8; ++nt) acc[nt] = (f4v){0.f, 0.f, 0.f, 0.f};
#pragma unroll
    for (int s = 0; s < 4; ++s) {
        s8v a = *(const s8v*)&sX[(w * 16 + mrow) * LW + s * 32 + quad * 8];
#pragma unroll
        for (int nt = 0; nt < 8; ++nt) {
            s8v b = *(const s8v*)&sW[(nt * 16 + mrow) * LW + s * 32 + quad * 8];
            acc[nt] = __builtin_amdgcn_mfma_f32_16x16x32_bf16(a, b, acc[nt], 0, 0, 0);
        }
    }

    u16* out = (wsel == 0) ? g_xl
             : (wsel <= R) ? g_P + (size_t)(wsel - 1) * NN * D
                           : g_Q + (size_t)(wsel - 1 - R) * NN * D;
#pragma unroll
    for (int nt = 0; nt < 8; ++nt) {
        int col = nt * 16 + mrow;
        float bias = (wsel == 0) ? bl[col] : 0.f;
#pragma unroll
        for (int r = 0; r < 4; ++r) {
            int row = n0 + w * 16 + quad * 4 + r;
            out[(size_t)row * D + col] = f2bs(acc[nt][r] + bias);
        }
    }
}

// ---- fused edge kernel (MFMA): 64 edges/block, 4 waves x 16-edge M-tiles ----
__global__ __launch_bounds__(256) void k_edge(
        const float* __restrict__ att, const int* __restrict__ ei,
        const int* __restrict__ et) {
    __shared__ __align__(16) short sWeT[D * LW];   // 34816 B
    __shared__ __align__(16) short sEa[64 * LW];   // 17408 B
    __shared__ float als[64][H];
    __shared__ int es[64], ed[64], er[64];
    const int tid = threadIdx.x;
    const int e0 = blockIdx.x * 64;
    const u16* WeT = g_Wn + (size_t)11 * D * D;

    if (tid < 64) {
        es[tid] = ei[e0 + tid];
        ed[tid] = ei[NE + e0 + tid];
        er[tid] = et[e0 + tid];
    }
#pragma unroll
    for (int i = 0; i < 8; ++i) {
        int flat = i * 256 + tid;
        int n = flat >> 4, c8 = (flat & 15) << 3;
        *(uint4*)&sWeT[n * LW + c8] = *(const uint4*)&WeT[n * D + c8];
    }
    __syncthreads();

    // ea = gelu(P[src]+Q[dst]) -> bf16 LDS
#pragma unroll
    for (int i = 0; i < 16; ++i) {
        int flat = i * 256 + tid;
        int row = flat >> 6;
        int cp = (flat & 63) << 1;
        size_t pb = ((size_t)er[row] * NN + es[row]) * D + cp;
        size_t qb = ((size_t)er[row] * NN + ed[row]) * D + cp;
        u32 pu = *(const u32*)&g_P[pb];
        u32 qu = *(const u32*)&g_Q[qb];
        float v0 = gelu_f(bflo(pu) + bflo(qu));
        float v1 = gelu_f(bfhi(pu) + bfhi(qu));
        ((u32*)sEa)[row * (LW / 2) + (cp >> 1)] = pack2(v0, v1);
    }
    __syncthreads();

    const int l = tid & 63, w = tid >> 6;
    const int mrow = l & 15, quad = l >> 4;
    f4v acc[8];
#pragma unroll
    for (int nt = 0; nt < 8; ++nt) acc[nt] = (f4v){0.f, 0.f, 0.f, 0.f};
#pragma unroll
    for (int s = 0; s < 4; ++s) {
        s8v a = *(const s8v*)&sEa[(w * 16 + mrow) * LW + s * 32 + quad * 8];
#pragma unroll
        for (int nt = 0; nt < 8; ++nt) {
            s8v b = *(const s8v*)&sWeT[(nt * 16 + mrow) * LW + s * 32 + quad * 8];
            acc[nt] = __builtin_amdgcn_mfma_f32_16x16x32_bf16(a, b, acc[nt], 0, 0, 0);
        }
    }

    // epilogue in C-layout: edge = w*16 + quad*4 + r, col = nt*16 + mrow
    float hsum[4][4];
#pragma unroll
    for (int r = 0; r < 4; ++r)
#pragma unroll
        for (int h = 0; h < 4; ++h) hsum[r][h] = 0.f;
#pragma unroll
    for (int nt = 0; nt < 8; ++nt) {
        int col = nt * 16 + mrow;
        float av = att[col];
        int h = nt >> 1;
#pragma unroll
        for (int r = 0; r < 4; ++r) {
            int el = w * 16 + quad * 4 + r;
            float m = acc[nt][r]
                    + us2f(g_xl[(size_t)es[el] * D + col])
                    + us2f(g_xl[(size_t)ed[el] * D + col]);
            float lr = m > 0.f ? m : 0.2f * m;
            hsum[r][h] = fmaf(lr, av, hsum[r][h]);
        }
    }
#pragma unroll
    for (int r = 0; r < 4; ++r)
#pragma unroll
        for (int h = 0; h < 4; ++h) {
            float v = hsum[r][h];
            v += __shfl_xor(v, 1); v += __shfl_xor(v, 2);
            v += __shfl_xor(v, 4); v += __shfl_xor(v, 8);
            hsum[r][h] = v;
        }
    if (mrow == 0) {
#pragma unroll
        for (int r = 0; r < 4; ++r)
#pragma unroll
            for (int h = 0; h < 4; ++h)
                als[w * 16 + quad * 4 + r][h] = hsum[r][h];
    }
    __syncthreads();

    {
        int el = tid >> 2, h = tid & 3;
        float a = als[el][h];
        g_araw[(size_t)(e0 + el) * H + h] = a;
        atomicMax(&g_nmax[(size_t)ed[el] * H + h], enc_max(a));
    }
}

// ---- denom pass ----
__global__ void k_denom(const int* __restrict__ ei) {
    int idx = blockIdx.x * 256 + threadIdx.x;   // NE*H total
    int e = idx >> 2, h = idx & 3;
    int d = ei[NE + e];
    float mx = dec_max(g_nmax[(size_t)d * H + h]);
    atomicAdd(&g_den[(size_t)d * H + h], __expf(g_araw[idx] - mx));
}

// ---- aggregation: acc[dst] += xl[src] * alpha ----
__global__ void k_aggr(const int* __restrict__ ei) {
    int tid = threadIdx.x;
    int e = blockIdx.x * 2 + (tid >> 7);
    int j = tid & 127;
    int s = ei[e], d = ei[NE + e];
    int h = j >> 5;
    float mx = dec_max(g_nmax[(size_t)d * H + h]);
    float a = __expf(g_araw[(size_t)e * H + h] - mx);
    float cf = a / (g_den[(size_t)d * H + h] + 1e-16f);
    float v = us2f(g_xl[(size_t)s * D + j]) * cf;
    atomicAdd(&g_acc[(size_t)d * D + j], v);
}

// ---- finalize: x = act(acc + bias) ----
__global__ void k_fin(const float* __restrict__ bias, int do_gelu) {
    int idx = blockIdx.x * 256 + threadIdx.x;
    float v = g_acc[idx] + bias[idx & 127];
    g_x[idx] = do_gelu ? gelu_f(v) : v;
}

// ---- output head: y = x[:BS]@out_w + out_b ; LayerNorm(eps=1e-12) ----
__global__ void k_head(const float* __restrict__ ow, const float* __restrict__ ob,
                       const float* __restrict__ g, const float* __restrict__ b,
                       float* __restrict__ out) {
    __shared__ float xs[D];
    __shared__ float red[D];
    int j = threadIdx.x, row = blockIdx.x;
    xs[j] = g_x[(size_t)row * D + j];
    __syncthreads();
    float y = ob[j];
#pragma unroll 8
    for (int k = 0; k < D; ++k) y = fmaf(xs[k], ow[k * D + j], y);
    red[j] = y;
    __syncthreads();
    for (int s = 64; s > 0; s >>= 1) { if (j < s) red[j] += red[j + s]; __syncthreads(); }
    float mu = red[0] * (1.f / D);
    __syncthreads();
    float dv = y - mu;
    red[j] = dv * dv;
    __syncthreads();
    for (int s = 64; s > 0; s >>= 1) { if (j < s) red[j] += red[j + s]; __syncthreads(); }
    float var = red[0] * (1.f / D);
    out[(size_t)row * D + j] = dv * rsqrtf(var + 1e-12f) * g[j] + b[j];
}

extern "C" void kernel_launch(void* const* d_in, const int* in_sizes, int n_in,
                              void* d_out, int out_size, void* d_ws, size_t ws_size,
                              hipStream_t stream) {
    (void)in_sizes; (void)n_in; (void)out_size; (void)d_ws; (void)ws_size;
    const float* embs = (const float*)d_in[0];
    const int*   ei   = (const int*)d_in[1];
    const int*   et   = (const int*)d_in[2];
    const float* rel  = (const float*)d_in[3];
    const float* wl[2]   = { (const float*)d_in[4],  (const float*)d_in[9]  };
    const float* bl[2]   = { (const float*)d_in[5],  (const float*)d_in[10] };
    const float* we[2]   = { (const float*)d_in[6],  (const float*)d_in[11] };
    const float* attw[2] = { (const float*)d_in[7],  (const float*)d_in[12] };
    const float* bs[2]   = { (const float*)d_in[8],  (const float*)d_in[13] };
    const float* ow  = (const float*)d_in[14];
    const float* ob  = (const float*)d_in[15];
    const float* lng = (const float*)d_in[16];
    const float* lnb = (const float*)d_in[17];
    float* out = (float*)d_out;

    k_cvt<<<NN * D / 256, 256, 0, stream>>>(embs);

    for (int l = 0; l < 2; ++l) {
        const float* Rm = rel + (size_t)l * R * 2 * D * D;
        k_prep<<<dim3(D * D / 256, 12), 256, 0, stream>>>(wl[l], Rm, we[l]);
        k_node<<<dim3(NN / 64, 11), 256, 0, stream>>>(bl[l]);
        k_zero<<<NN * D / 256, 256, 0, stream>>>();
        k_edge<<<NE / 64, 256, 0, stream>>>(attw[l], ei, et);
        k_denom<<<NE * H / 256, 256, 0, stream>>>(ei);
        k_aggr<<<NE / 2, 256, 0, stream>>>(ei);
        k_fin<<<NN * D / 256, 256, 0, stream>>>(bs[l], l == 0 ? 1 : 0);
    }

    k_head<<<BS, 128, 0, stream>>>(ow, ob, lng, lnb, out);
}

// Round 6
// 905.110 us; speedup vs baseline: 3.6311x; 1.4477x over previous
//
#include <hip/hip_runtime.h>
#include <hip/hip_bf16.h>

typedef __hip_bfloat16 bf16;
typedef __attribute__((ext_vector_type(8))) short s8v;
typedef __attribute__((ext_vector_type(4))) float f4v;
typedef unsigned short u16;
typedef unsigned int u32;

#define NN 32768
#define NE 524288
#define D 128
#define H 4
#define C 32
#define R 5
#define BS 8192
#define LW 136   // padded LDS row stride (bf16 elems)

__device__ __forceinline__ float b2f(bf16 x) { return __bfloat162float(x); }
__device__ __forceinline__ bf16 f2b(float x) { return __float2bfloat16(x); }
__device__ __forceinline__ u16 f2bs(float x) { bf16 h = f2b(x); return *(u16*)&h; }
__device__ __forceinline__ float us2f(u16 u) { return __uint_as_float(((u32)u) << 16); }
__device__ __forceinline__ float bflo(u32 u) { return __uint_as_float(u << 16); }
__device__ __forceinline__ float bfhi(u32 u) { return __uint_as_float(u & 0xffff0000u); }
__device__ __forceinline__ u32 pack2(float a, float b) {
    return (u32)f2bs(a) | ((u32)f2bs(b) << 16);
}
__device__ __forceinline__ float gelu_f(float x) {
    return 0.5f * x * (1.f + erff(x * 0.7071067811865475f));
}

// ---- static device scratch ----
__device__ float    g_x[NN * D];        // f32 working activations
__device__ float    g_araw[NE * H];     // raw attention logits
__device__ u16      g_P[R * NN * D];    // bf16: x @ Rtop[r]
__device__ u16      g_Q[R * NN * D];    // bf16: x @ Rbot[r]
__device__ u16      g_xl[NN * D];       // bf16: x @ Wl + bl
__device__ u16      g_Wn[12 * D * D];   // bf16 transposed weights: Wl,Rtop[5],Rbot[5],We
__device__ int      g_cnt[NN];          // CSR: in-degree counts
__device__ int      g_cur[NN];          // CSR: scatter cursors
__device__ int      g_off[NN + 1];      // CSR: row offsets (by dst)
__device__ int      g_eidx[NE];         // CSR: edge ids sorted by dst

__global__ void k_cvt(const float* __restrict__ e) {
    int i = blockIdx.x * 256 + threadIdx.x;
    g_x[i] = e[i];
}

// ---- CSR build (edge list identical for both layers: build once) ----
__global__ void k_zcnt() {
    int i = blockIdx.x * 256 + threadIdx.x;   // NN threads
    g_cnt[i] = 0; g_cur[i] = 0;
}
__global__ void k_count(const int* __restrict__ ei) {
    int i = blockIdx.x * 256 + threadIdx.x;   // NE threads
    atomicAdd(&g_cnt[ei[NE + i]], 1);
}
__global__ void k_scan() {   // 1 block, 1024 threads, 32 elems each
    __shared__ int sums[1024];
    const int t = threadIdx.x;
    const int base = t * 32;
    int local[32];
    int s = 0;
#pragma unroll
    for (int i = 0; i < 32; ++i) { local[i] = s; s += g_cnt[base + i]; }
    sums[t] = s;
    __syncthreads();
    for (int off = 1; off < 1024; off <<= 1) {
        int v = (t >= off) ? sums[t - off] : 0;
        __syncthreads();
        sums[t] += v;
        __syncthreads();
    }
    int chunkoff = (t == 0) ? 0 : sums[t - 1];
#pragma unroll
    for (int i = 0; i < 32; ++i) g_off[base + i] = chunkoff + local[i];
    if (t == 1023) g_off[NN] = sums[1023];
}
__global__ void k_scatter(const int* __restrict__ ei) {
    int i = blockIdx.x * 256 + threadIdx.x;   // NE threads
    int d = ei[NE + i];
    int pos = atomicAdd(&g_cur[d], 1);
    g_eidx[g_off[d] + pos] = i;
}

// ---- transpose + bf16-cast all 12 weight matrices: Wt[n][k] = W[k][n] ----
__global__ void k_prep(const float* __restrict__ Wl, const float* __restrict__ Rm,
                       const float* __restrict__ We) {
    int i = blockIdx.x * 256 + threadIdx.x;   // source element
    int y = blockIdx.y;
    int k = i >> 7, n = i & 127;
    const float* src;
    if (y == 0) src = Wl;
    else if (y <= R) src = Rm + (size_t)(y - 1) * 2 * D * D;
    else if (y <= 2 * R) src = Rm + (size_t)(y - 1 - R) * 2 * D * D + D * D;
    else src = We;
    g_Wn[(size_t)y * D * D + n * D + k] = f2bs(src[i]);
}

// ---- node transforms (MFMA): xl / P[r] / Q[r] = x @ W (+ bias for xl) ----
// grid: (NN/64, 11), block 256 (4 waves x 16-node tiles)
__global__ __launch_bounds__(256) void k_node(const float* __restrict__ bl) {
    __shared__ __align__(16) short sX[64 * LW];
    __shared__ __align__(16) short sW[D * LW];
    const int tid = threadIdx.x;
    const int n0 = blockIdx.x * 64;
    const int wsel = blockIdx.y;

#pragma unroll
    for (int i = 0; i < 16; ++i) {
        int flat = i * 256 + tid;
        int row = flat >> 6, cp = (flat & 63) << 1;
        const float2 v = *(const float2*)&g_x[(size_t)(n0 + row) * D + cp];
        ((u32*)sX)[row * (LW / 2) + (cp >> 1)] = pack2(v.x, v.y);
    }
    const u16* Wt = g_Wn + (size_t)wsel * D * D;
#pragma unroll
    for (int i = 0; i < 8; ++i) {
        int flat = i * 256 + tid;
        int n = flat >> 4, c8 = (flat & 15) << 3;
        *(uint4*)&sW[n * LW + c8] = *(const uint4*)&Wt[n * D + c8];
    }
    __syncthreads();

    const int l = tid & 63, w = tid >> 6;
    const int mrow = l & 15, quad = l >> 4;
    f4v acc[8];
#pragma unroll
    for (int nt = 0; nt < 8; ++nt) acc[nt] = (f4v){0.f, 0.f, 0.f, 0.f};
#pragma unroll
    for (int s = 0; s < 4; ++s) {
        s8v a = *(const s8v*)&sX[(w * 16 + mrow) * LW + s * 32 + quad * 8];
#pragma unroll
        for (int nt = 0; nt < 8; ++nt) {
            s8v b = *(const s8v*)&sW[(nt * 16 + mrow) * LW + s * 32 + quad * 8];
            acc[nt] = __builtin_amdgcn_mfma_f32_16x16x32_bf16(a, b, acc[nt], 0, 0, 0);
        }
    }

    u16* out = (wsel == 0) ? g_xl
             : (wsel <= R) ? g_P + (size_t)(wsel - 1) * NN * D
                           : g_Q + (size_t)(wsel - 1 - R) * NN * D;
#pragma unroll
    for (int nt = 0; nt < 8; ++nt) {
        int col = nt * 16 + mrow;
        float bias = (wsel == 0) ? bl[col] : 0.f;
#pragma unroll
        for (int r = 0; r < 4; ++r) {
            int row = n0 + w * 16 + quad * 4 + r;
            out[(size_t)row * D + col] = f2bs(acc[nt][r] + bias);
        }
    }
}

// ---- fused edge kernel (MFMA): logits only (no atomics now) ----
__global__ __launch_bounds__(256) void k_edge(
        const float* __restrict__ att, const int* __restrict__ ei,
        const int* __restrict__ et) {
    __shared__ __align__(16) short sWeT[D * LW];
    __shared__ __align__(16) short sEa[64 * LW];
    __shared__ float als[64][H];
    __shared__ int es[64], ed[64], er[64];
    const int tid = threadIdx.x;
    const int e0 = blockIdx.x * 64;
    const u16* WeT = g_Wn + (size_t)11 * D * D;

    if (tid < 64) {
        es[tid] = ei[e0 + tid];
        ed[tid] = ei[NE + e0 + tid];
        er[tid] = et[e0 + tid];
    }
#pragma unroll
    for (int i = 0; i < 8; ++i) {
        int flat = i * 256 + tid;
        int n = flat >> 4, c8 = (flat & 15) << 3;
        *(uint4*)&sWeT[n * LW + c8] = *(const uint4*)&WeT[n * D + c8];
    }
    __syncthreads();

#pragma unroll
    for (int i = 0; i < 16; ++i) {
        int flat = i * 256 + tid;
        int row = flat >> 6;
        int cp = (flat & 63) << 1;
        size_t pb = ((size_t)er[row] * NN + es[row]) * D + cp;
        size_t qb = ((size_t)er[row] * NN + ed[row]) * D + cp;
        u32 pu = *(const u32*)&g_P[pb];
        u32 qu = *(const u32*)&g_Q[qb];
        float v0 = gelu_f(bflo(pu) + bflo(qu));
        float v1 = gelu_f(bfhi(pu) + bfhi(qu));
        ((u32*)sEa)[row * (LW / 2) + (cp >> 1)] = pack2(v0, v1);
    }
    __syncthreads();

    const int l = tid & 63, w = tid >> 6;
    const int mrow = l & 15, quad = l >> 4;
    f4v acc[8];
#pragma unroll
    for (int nt = 0; nt < 8; ++nt) acc[nt] = (f4v){0.f, 0.f, 0.f, 0.f};
#pragma unroll
    for (int s = 0; s < 4; ++s) {
        s8v a = *(const s8v*)&sEa[(w * 16 + mrow) * LW + s * 32 + quad * 8];
#pragma unroll
        for (int nt = 0; nt < 8; ++nt) {
            s8v b = *(const s8v*)&sWeT[(nt * 16 + mrow) * LW + s * 32 + quad * 8];
            acc[nt] = __builtin_amdgcn_mfma_f32_16x16x32_bf16(a, b, acc[nt], 0, 0, 0);
        }
    }

    float hsum[4][4];
#pragma unroll
    for (int r = 0; r < 4; ++r)
#pragma unroll
        for (int h = 0; h < 4; ++h) hsum[r][h] = 0.f;
#pragma unroll
    for (int nt = 0; nt < 8; ++nt) {
        int col = nt * 16 + mrow;
        float av = att[col];
        int h = nt >> 1;
#pragma unroll
        for (int r = 0; r < 4; ++r) {
            int el = w * 16 + quad * 4 + r;
            float m = acc[nt][r]
                    + us2f(g_xl[(size_t)es[el] * D + col])
                    + us2f(g_xl[(size_t)ed[el] * D + col]);
            float lr = m > 0.f ? m : 0.2f * m;
            hsum[r][h] = fmaf(lr, av, hsum[r][h]);
        }
    }
#pragma unroll
    for (int r = 0; r < 4; ++r)
#pragma unroll
        for (int h = 0; h < 4; ++h) {
            float v = hsum[r][h];
            v += __shfl_xor(v, 1); v += __shfl_xor(v, 2);
            v += __shfl_xor(v, 4); v += __shfl_xor(v, 8);
            hsum[r][h] = v;
        }
    if (mrow == 0) {
#pragma unroll
        for (int r = 0; r < 4; ++r)
#pragma unroll
            for (int h = 0; h < 4; ++h)
                als[w * 16 + quad * 4 + r][h] = hsum[r][h];
    }
    __syncthreads();

    {
        int el = tid >> 2, h = tid & 3;
        g_araw[(size_t)(e0 + el) * H + h] = als[el][h];
    }
}

// ---- fused gather: per-dst softmax (max+denom) + aggregation + bias + act ----
// one wave per dst; block 256 = 4 dsts; grid NN/4
__global__ __launch_bounds__(256) void k_gath(const int* __restrict__ ei,
                                              const float* __restrict__ bias,
                                              int do_gelu) {
    const int lane = threadIdx.x & 63;
    const int d = blockIdx.x * 4 + (threadIdx.x >> 6);
    const int off = g_off[d];
    const int deg = g_off[d + 1] - off;
    const int h = lane >> 4;        // head for cols 2*lane, 2*lane+1
    const int slot = lane & 15;

    // per-head segment max (over slot lanes)
    float mx = -3.4e38f;
    for (int p = slot; p < deg; p += 16)
        mx = fmaxf(mx, g_araw[(size_t)g_eidx[off + p] * H + h]);
    mx = fmaxf(mx, __shfl_xor(mx, 1));
    mx = fmaxf(mx, __shfl_xor(mx, 2));
    mx = fmaxf(mx, __shfl_xor(mx, 4));
    mx = fmaxf(mx, __shfl_xor(mx, 8));

    // per-head denom
    float den = 0.f;
    for (int p = slot; p < deg; p += 16)
        den += __expf(g_araw[(size_t)g_eidx[off + p] * H + h] - mx);
    den += __shfl_xor(den, 1);
    den += __shfl_xor(den, 2);
    den += __shfl_xor(den, 4);
    den += __shfl_xor(den, 8);
    const float inv = 1.f / (den + 1e-16f);

    // aggregate: cols (2*lane, 2*lane+1)
    float a0 = 0.f, a1 = 0.f;
    for (int p = 0; p < deg; ++p) {
        int e = g_eidx[off + p];
        int s = ei[e];
        float cf = __expf(g_araw[(size_t)e * H + h] - mx) * inv;
        u32 w = *(const u32*)&g_xl[(size_t)s * D + lane * 2];
        a0 = fmaf(bflo(w), cf, a0);
        a1 = fmaf(bfhi(w), cf, a1);
    }
    float v0 = a0 + bias[lane * 2];
    float v1 = a1 + bias[lane * 2 + 1];
    if (do_gelu) { v0 = gelu_f(v0); v1 = gelu_f(v1); }
    *(float2*)&g_x[(size_t)d * D + lane * 2] = make_float2(v0, v1);
}

// ---- output head: y = x[:BS]@out_w + out_b ; LayerNorm(eps=1e-12) ----
__global__ void k_head(const float* __restrict__ ow, const float* __restrict__ ob,
                       const float* __restrict__ g, const float* __restrict__ b,
                       float* __restrict__ out) {
    __shared__ float xs[D];
    __shared__ float red[D];
    int j = threadIdx.x, row = blockIdx.x;
    xs[j] = g_x[(size_t)row * D + j];
    __syncthreads();
    float y = ob[j];
#pragma unroll 8
    for (int k = 0; k < D; ++k) y = fmaf(xs[k], ow[k * D + j], y);
    red[j] = y;
    __syncthreads();
    for (int s = 64; s > 0; s >>= 1) { if (j < s) red[j] += red[j + s]; __syncthreads(); }
    float mu = red[0] * (1.f / D);
    __syncthreads();
    float dv = y - mu;
    red[j] = dv * dv;
    __syncthreads();
    for (int s = 64; s > 0; s >>= 1) { if (j < s) red[j] += red[j + s]; __syncthreads(); }
    float var = red[0] * (1.f / D);
    out[(size_t)row * D + j] = dv * rsqrtf(var + 1e-12f) * g[j] + b[j];
}

extern "C" void kernel_launch(void* const* d_in, const int* in_sizes, int n_in,
                              void* d_out, int out_size, void* d_ws, size_t ws_size,
                              hipStream_t stream) {
    (void)in_sizes; (void)n_in; (void)out_size; (void)d_ws; (void)ws_size;
    const float* embs = (const float*)d_in[0];
    const int*   ei   = (const int*)d_in[1];
    const int*   et   = (const int*)d_in[2];
    const float* rel  = (const float*)d_in[3];
    const float* wl[2]   = { (const float*)d_in[4],  (const float*)d_in[9]  };
    const float* bl[2]   = { (const float*)d_in[5],  (const float*)d_in[10] };
    const float* we[2]   = { (const float*)d_in[6],  (const float*)d_in[11] };
    const float* attw[2] = { (const float*)d_in[7],  (const float*)d_in[12] };
    const float* bs[2]   = { (const float*)d_in[8],  (const float*)d_in[13] };
    const float* ow  = (const float*)d_in[14];
    const float* ob  = (const float*)d_in[15];
    const float* lng = (const float*)d_in[16];
    const float* lnb = (const float*)d_in[17];
    float* out = (float*)d_out;

    k_cvt<<<NN * D / 256, 256, 0, stream>>>(embs);

    // CSR by dst (edge list shared by both layers)
    k_zcnt<<<NN / 256, 256, 0, stream>>>();
    k_count<<<NE / 256, 256, 0, stream>>>(ei);
    k_scan<<<1, 1024, 0, stream>>>();
    k_scatter<<<NE / 256, 256, 0, stream>>>(ei);

    for (int l = 0; l < 2; ++l) {
        const float* Rm = rel + (size_t)l * R * 2 * D * D;
        k_prep<<<dim3(D * D / 256, 12), 256, 0, stream>>>(wl[l], Rm, we[l]);
        k_node<<<dim3(NN / 64, 11), 256, 0, stream>>>(bl[l]);
        k_edge<<<NE / 64, 256, 0, stream>>>(attw[l], ei, et);
        k_gath<<<NN / 4, 256, 0, stream>>>(ei, bs[l], l == 0 ? 1 : 0);
    }

    k_head<<<BS, 128, 0, stream>>>(ow, ob, lng, lnb, out);
}

// Round 7
// 687.435 us; speedup vs baseline: 4.7809x; 1.3166x over previous
//
#include <hip/hip_runtime.h>
#include <hip/hip_bf16.h>

typedef __hip_bfloat16 bf16;
typedef __attribute__((ext_vector_type(8))) short s8v;
typedef __attribute__((ext_vector_type(4))) float f4v;
typedef unsigned short u16;
typedef unsigned int u32;

#define NN 32768
#define NE 524288
#define D 128
#define H 4
#define C 32
#define R 5
#define BS 8192
#define LW 136   // padded LDS row stride (bf16 elems)

__device__ __forceinline__ float b2f(bf16 x) { return __bfloat162float(x); }
__device__ __forceinline__ bf16 f2b(float x) { return __float2bfloat16(x); }
__device__ __forceinline__ u16 f2bs(float x) { bf16 h = f2b(x); return *(u16*)&h; }
__device__ __forceinline__ float us2f(u16 u) { return __uint_as_float(((u32)u) << 16); }
__device__ __forceinline__ float bflo(u32 u) { return __uint_as_float(u << 16); }
__device__ __forceinline__ float bfhi(u32 u) { return __uint_as_float(u & 0xffff0000u); }
__device__ __forceinline__ u32 pack2(float a, float b) {
    return (u32)f2bs(a) | ((u32)f2bs(b) << 16);
}
__device__ __forceinline__ float gelu_f(float x) {
    return 0.5f * x * (1.f + erff(x * 0.7071067811865475f));
}

// ---- static device scratch ----
__device__ float    g_x[NN * D];        // f32 working activations
__device__ float    g_araw[NE * H];     // attention logits, CSR-position indexed
__device__ u16      g_P[R * NN * D];    // bf16: x @ Rtop[r]
__device__ u16      g_Q[R * NN * D];    // bf16: x @ Rbot[r]
__device__ u16      g_xl[NN * D];       // bf16: x @ Wl + bl
__device__ u16      g_Wn[12 * D * D];   // bf16 transposed weights: Wl,Rtop[5],Rbot[5],We
__device__ int      g_cnt[NN];          // CSR: in-degree counts
__device__ int      g_cur[NN];          // CSR: scatter cursors
__device__ int      g_off[NN + 1];      // CSR: row offsets (by dst)
__device__ int      g_eidx[NE];         // CSR: edge ids sorted by dst

__global__ void k_cvt(const float* __restrict__ e) {
    int i = blockIdx.x * 256 + threadIdx.x;
    g_x[i] = e[i];
}

// ---- CSR build (edge list identical for both layers: build once) ----
__global__ void k_zcnt() {
    int i = blockIdx.x * 256 + threadIdx.x;   // NN threads
    g_cnt[i] = 0; g_cur[i] = 0;
}
__global__ void k_count(const int* __restrict__ ei) {
    int i = blockIdx.x * 256 + threadIdx.x;   // NE threads
    atomicAdd(&g_cnt[ei[NE + i]], 1);
}
__global__ void k_scan() {   // 1 block, 1024 threads, 32 elems each
    __shared__ int sums[1024];
    const int t = threadIdx.x;
    const int base = t * 32;
    int local[32];
    int s = 0;
#pragma unroll
    for (int i = 0; i < 32; ++i) { local[i] = s; s += g_cnt[base + i]; }
    sums[t] = s;
    __syncthreads();
    for (int off = 1; off < 1024; off <<= 1) {
        int v = (t >= off) ? sums[t - off] : 0;
        __syncthreads();
        sums[t] += v;
        __syncthreads();
    }
    int chunkoff = (t == 0) ? 0 : sums[t - 1];
#pragma unroll
    for (int i = 0; i < 32; ++i) g_off[base + i] = chunkoff + local[i];
    if (t == 1023) g_off[NN] = sums[1023];
}
__global__ void k_scatter(const int* __restrict__ ei) {
    int i = blockIdx.x * 256 + threadIdx.x;   // NE threads
    int d = ei[NE + i];
    int pos = atomicAdd(&g_cur[d], 1);
    g_eidx[g_off[d] + pos] = i;
}

// ---- transpose + bf16-cast all 12 weight matrices: Wt[n][k] = W[k][n] ----
__global__ void k_prep(const float* __restrict__ Wl, const float* __restrict__ Rm,
                       const float* __restrict__ We) {
    int i = blockIdx.x * 256 + threadIdx.x;   // source element
    int y = blockIdx.y;
    int k = i >> 7, n = i & 127;
    const float* src;
    if (y == 0) src = Wl;
    else if (y <= R) src = Rm + (size_t)(y - 1) * 2 * D * D;
    else if (y <= 2 * R) src = Rm + (size_t)(y - 1 - R) * 2 * D * D + D * D;
    else src = We;
    g_Wn[(size_t)y * D * D + n * D + k] = f2bs(src[i]);
}

// ---- node transforms (MFMA): xl / P[r] / Q[r] = x @ W (+ bias for xl) ----
// grid: (NN/64, 11), block 256 (4 waves x 16-node tiles)
__global__ __launch_bounds__(256) void k_node(const float* __restrict__ bl) {
    __shared__ __align__(16) short sX[64 * LW];
    __shared__ __align__(16) short sW[D * LW];
    const int tid = threadIdx.x;
    const int n0 = blockIdx.x * 64;
    const int wsel = blockIdx.y;

#pragma unroll
    for (int i = 0; i < 16; ++i) {
        int flat = i * 256 + tid;
        int row = flat >> 6, cp = (flat & 63) << 1;
        const float2 v = *(const float2*)&g_x[(size_t)(n0 + row) * D + cp];
        ((u32*)sX)[row * (LW / 2) + (cp >> 1)] = pack2(v.x, v.y);
    }
    const u16* Wt = g_Wn + (size_t)wsel * D * D;
#pragma unroll
    for (int i = 0; i < 8; ++i) {
        int flat = i * 256 + tid;
        int n = flat >> 4, c8 = (flat & 15) << 3;
        *(uint4*)&sW[n * LW + c8] = *(const uint4*)&Wt[n * D + c8];
    }
    __syncthreads();

    const int l = tid & 63, w = tid >> 6;
    const int mrow = l & 15, quad = l >> 4;
    f4v acc[8];
#pragma unroll
    for (int nt = 0; nt < 8; ++nt) acc[nt] = (f4v){0.f, 0.f, 0.f, 0.f};
#pragma unroll
    for (int s = 0; s < 4; ++s) {
        s8v a = *(const s8v*)&sX[(w * 16 + mrow) * LW + s * 32 + quad * 8];
#pragma unroll
        for (int nt = 0; nt < 8; ++nt) {
            s8v b = *(const s8v*)&sW[(nt * 16 + mrow) * LW + s * 32 + quad * 8];
            acc[nt] = __builtin_amdgcn_mfma_f32_16x16x32_bf16(a, b, acc[nt], 0, 0, 0);
        }
    }

    u16* out = (wsel == 0) ? g_xl
             : (wsel <= R) ? g_P + (size_t)(wsel - 1) * NN * D
                           : g_Q + (size_t)(wsel - 1 - R) * NN * D;
#pragma unroll
    for (int nt = 0; nt < 8; ++nt) {
        int col = nt * 16 + mrow;
        float bias = (wsel == 0) ? bl[col] : 0.f;
#pragma unroll
        for (int r = 0; r < 4; ++r) {
            int row = n0 + w * 16 + quad * 4 + r;
            out[(size_t)row * D + col] = f2bs(acc[nt][r] + bias);
        }
    }
}

// ---- fused edge kernel (MFMA, CSR-ordered, direct A-frags) ----
// block = 64 CSR positions (4 waves x 16 edges); logits -> g_araw[pos]
__global__ __launch_bounds__(256) void k_edge(
        const float* __restrict__ att, const int* __restrict__ ei,
        const int* __restrict__ et) {
    __shared__ __align__(16) short sWeT[D * LW];   // 34816 B
    __shared__ float als[64][H];
    __shared__ int es[64], ed[64], er[64];
    const int tid = threadIdx.x;
    const int e0 = blockIdx.x * 64;
    const u16* WeT = g_Wn + (size_t)11 * D * D;

    if (tid < 64) {
        int e = g_eidx[e0 + tid];
        es[tid] = ei[e];
        ed[tid] = ei[NE + e];
        er[tid] = et[e];
    }
#pragma unroll
    for (int i = 0; i < 8; ++i) {
        int flat = i * 256 + tid;
        int n = flat >> 4, c8 = (flat & 15) << 3;
        *(uint4*)&sWeT[n * LW + c8] = *(const uint4*)&WeT[n * D + c8];
    }
    __syncthreads();

    const int l = tid & 63, w = tid >> 6;
    const int mrow = l & 15, quad = l >> 4;

    // direct A-fragments: row = my edge, cols s*32 + quad*8 .. +7
    const int myrow = w * 16 + mrow;
    const u16* Prow = g_P + ((size_t)er[myrow] * NN + es[myrow]) * D;
    const u16* Qrow = g_Q + ((size_t)er[myrow] * NN + ed[myrow]) * D;
    union { u32 u[4]; s8v v; } af[4];
#pragma unroll
    for (int s = 0; s < 4; ++s) {
        int c0 = s * 32 + quad * 8;
        uint4 pu = *(const uint4*)&Prow[c0];
        uint4 qu = *(const uint4*)&Qrow[c0];
        af[s].u[0] = pack2(gelu_f(bflo(pu.x) + bflo(qu.x)), gelu_f(bfhi(pu.x) + bfhi(qu.x)));
        af[s].u[1] = pack2(gelu_f(bflo(pu.y) + bflo(qu.y)), gelu_f(bfhi(pu.y) + bfhi(qu.y)));
        af[s].u[2] = pack2(gelu_f(bflo(pu.z) + bflo(qu.z)), gelu_f(bfhi(pu.z) + bfhi(qu.z)));
        af[s].u[3] = pack2(gelu_f(bflo(pu.w) + bflo(qu.w)), gelu_f(bfhi(pu.w) + bfhi(qu.w)));
    }

    f4v acc[8];
#pragma unroll
    for (int nt = 0; nt < 8; ++nt) acc[nt] = (f4v){0.f, 0.f, 0.f, 0.f};
#pragma unroll
    for (int s = 0; s < 4; ++s) {
#pragma unroll
        for (int nt = 0; nt < 8; ++nt) {
            s8v b = *(const s8v*)&sWeT[(nt * 16 + mrow) * LW + s * 32 + quad * 8];
            acc[nt] = __builtin_amdgcn_mfma_f32_16x16x32_bf16(af[s].v, b, acc[nt], 0, 0, 0);
        }
    }

    // epilogue in C-layout: edge = w*16 + quad*4 + r, col = nt*16 + mrow
    float hsum[4][4];
#pragma unroll
    for (int r = 0; r < 4; ++r)
#pragma unroll
        for (int h = 0; h < 4; ++h) hsum[r][h] = 0.f;
#pragma unroll
    for (int nt = 0; nt < 8; ++nt) {
        int col = nt * 16 + mrow;
        float av = att[col];
        int h = nt >> 1;
#pragma unroll
        for (int r = 0; r < 4; ++r) {
            int el = w * 16 + quad * 4 + r;
            float m = acc[nt][r]
                    + us2f(g_xl[(size_t)es[el] * D + col])
                    + us2f(g_xl[(size_t)ed[el] * D + col]);
            float lr = m > 0.f ? m : 0.2f * m;
            hsum[r][h] = fmaf(lr, av, hsum[r][h]);
        }
    }
#pragma unroll
    for (int r = 0; r < 4; ++r)
#pragma unroll
        for (int h = 0; h < 4; ++h) {
            float v = hsum[r][h];
            v += __shfl_xor(v, 1); v += __shfl_xor(v, 2);
            v += __shfl_xor(v, 4); v += __shfl_xor(v, 8);
            hsum[r][h] = v;
        }
    if (mrow == 0) {
#pragma unroll
        for (int r = 0; r < 4; ++r)
#pragma unroll
            for (int h = 0; h < 4; ++h)
                als[w * 16 + quad * 4 + r][h] = hsum[r][h];
    }
    __syncthreads();

    {   // position-indexed logit store (coalesced; k_gath reads contiguously)
        int el = tid >> 2, h = tid & 3;
        g_araw[(size_t)(e0 + el) * H + h] = als[el][h];
    }
}

// ---- fused gather: per-dst softmax (max+denom) + aggregation + bias + act ----
// one wave per dst; block 256 = 4 dsts; grid NN/4
__global__ __launch_bounds__(256) void k_gath(const int* __restrict__ ei,
                                              const float* __restrict__ bias,
                                              int do_gelu) {
    const int lane = threadIdx.x & 63;
    const int d = blockIdx.x * 4 + (threadIdx.x >> 6);
    const int off = g_off[d];
    const int deg = g_off[d + 1] - off;
    const int h = lane >> 4;        // head for cols 2*lane, 2*lane+1
    const int slot = lane & 15;

    // per-head segment max (coalesced: araw is CSR-position indexed)
    float mx = -3.4e38f;
    for (int p = slot; p < deg; p += 16)
        mx = fmaxf(mx, g_araw[(size_t)(off + p) * H + h]);
    mx = fmaxf(mx, __shfl_xor(mx, 1));
    mx = fmaxf(mx, __shfl_xor(mx, 2));
    mx = fmaxf(mx, __shfl_xor(mx, 4));
    mx = fmaxf(mx, __shfl_xor(mx, 8));

    // per-head denom
    float den = 0.f;
    for (int p = slot; p < deg; p += 16)
        den += __expf(g_araw[(size_t)(off + p) * H + h] - mx);
    den += __shfl_xor(den, 1);
    den += __shfl_xor(den, 2);
    den += __shfl_xor(den, 4);
    den += __shfl_xor(den, 8);
    const float inv = 1.f / (den + 1e-16f);

    // aggregate: cols (2*lane, 2*lane+1)
    float a0 = 0.f, a1 = 0.f;
    for (int p = 0; p < deg; ++p) {
        int s = ei[g_eidx[off + p]];
        float cf = __expf(g_araw[(size_t)(off + p) * H + h] - mx) * inv;
        u32 w = *(const u32*)&g_xl[(size_t)s * D + lane * 2];
        a0 = fmaf(bflo(w), cf, a0);
        a1 = fmaf(bfhi(w), cf, a1);
    }
    float v0 = a0 + bias[lane * 2];
    float v1 = a1 + bias[lane * 2 + 1];
    if (do_gelu) { v0 = gelu_f(v0); v1 = gelu_f(v1); }
    *(float2*)&g_x[(size_t)d * D + lane * 2] = make_float2(v0, v1);
}

// ---- output head: y = x[:BS]@out_w + out_b ; LayerNorm(eps=1e-12) ----
__global__ void k_head(const float* __restrict__ ow, const float* __restrict__ ob,
                       const float* __restrict__ g, const float* __restrict__ b,
                       float* __restrict__ out) {
    __shared__ float xs[D];
    __shared__ float red[D];
    int j = threadIdx.x, row = blockIdx.x;
    xs[j] = g_x[(size_t)row * D + j];
    __syncthreads();
    float y = ob[j];
#pragma unroll 8
    for (int k = 0; k < D; ++k) y = fmaf(xs[k], ow[k * D + j], y);
    red[j] = y;
    __syncthreads();
    for (int s = 64; s > 0; s >>= 1) { if (j < s) red[j] += red[j + s]; __syncthreads(); }
    float mu = red[0] * (1.f / D);
    __syncthreads();
    float dv = y - mu;
    red[j] = dv * dv;
    __syncthreads();
    for (int s = 64; s > 0; s >>= 1) { if (j < s) red[j] += red[j + s]; __syncthreads(); }
    float var = red[0] * (1.f / D);
    out[(size_t)row * D + j] = dv * rsqrtf(var + 1e-12f) * g[j] + b[j];
}

extern "C" void kernel_launch(void* const* d_in, const int* in_sizes, int n_in,
                              void* d_out, int out_size, void* d_ws, size_t ws_size,
                              hipStream_t stream) {
    (void)in_sizes; (void)n_in; (void)out_size; (void)d_ws; (void)ws_size;
    const float* embs = (const float*)d_in[0];
    const int*   ei   = (const int*)d_in[1];
    const int*   et   = (const int*)d_in[2];
    const float* rel  = (const float*)d_in[3];
    const float* wl[2]   = { (const float*)d_in[4],  (const float*)d_in[9]  };
    const float* bl[2]   = { (const float*)d_in[5],  (const float*)d_in[10] };
    const float* we[2]   = { (const float*)d_in[6],  (const float*)d_in[11] };
    const float* attw[2] = { (const float*)d_in[7],  (const float*)d_in[12] };
    const float* bs[2]   = { (const float*)d_in[8],  (const float*)d_in[13] };
    const float* ow  = (const float*)d_in[14];
    const float* ob  = (const float*)d_in[15];
    const float* lng = (const float*)d_in[16];
    const float* lnb = (const float*)d_in[17];
    float* out = (float*)d_out;

    k_cvt<<<NN * D / 256, 256, 0, stream>>>(embs);

    // CSR by dst (edge list shared by both layers)
    k_zcnt<<<NN / 256, 256, 0, stream>>>();
    k_count<<<NE / 256, 256, 0, stream>>>(ei);
    k_scan<<<1, 1024, 0, stream>>>();
    k_scatter<<<NE / 256, 256, 0, stream>>>(ei);

    for (int l = 0; l < 2; ++l) {
        const float* Rm = rel + (size_t)l * R * 2 * D * D;
        k_prep<<<dim3(D * D / 256, 12), 256, 0, stream>>>(wl[l], Rm, we[l]);
        k_node<<<dim3(NN / 64, 11), 256, 0, stream>>>(bl[l]);
        k_edge<<<NE / 64, 256, 0, stream>>>(attw[l], ei, et);
        k_gath<<<NN / 4, 256, 0, stream>>>(ei, bs[l], l == 0 ? 1 : 0);
    }

    k_head<<<BS, 128, 0, stream>>>(ow, ob, lng, lnb, out);
}

// Round 8
// 674.606 us; speedup vs baseline: 4.8718x; 1.0190x over previous
//
#include <hip/hip_runtime.h>
#include <hip/hip_bf16.h>

typedef __hip_bfloat16 bf16;
typedef __attribute__((ext_vector_type(8))) short s8v;
typedef __attribute__((ext_vector_type(4))) float f4v;
typedef unsigned short u16;
typedef unsigned int u32;

#define NN 32768
#define NE 524288
#define D 128
#define H 4
#define C 32
#define R 5
#define BS 8192
#define LW 136   // padded LDS row stride (bf16 elems)

__device__ __forceinline__ float b2f(bf16 x) { return __bfloat162float(x); }
__device__ __forceinline__ bf16 f2b(float x) { return __float2bfloat16(x); }
__device__ __forceinline__ u16 f2bs(float x) { bf16 h = f2b(x); return *(u16*)&h; }
__device__ __forceinline__ float us2f(u16 u) { return __uint_as_float(((u32)u) << 16); }
__device__ __forceinline__ float bflo(u32 u) { return __uint_as_float(u << 16); }
__device__ __forceinline__ float bfhi(u32 u) { return __uint_as_float(u & 0xffff0000u); }
__device__ __forceinline__ u32 pack2(float a, float b) {
    return (u32)f2bs(a) | ((u32)f2bs(b) << 16);
}
__device__ __forceinline__ float gelu_f(float x) {
    return 0.5f * x * (1.f + erff(x * 0.7071067811865475f));
}

// ---- static device scratch ----
__device__ float    g_x[NN * D];        // f32 working activations
__device__ float    g_araw[NE * H];     // attention logits, CSR-position indexed
__device__ u16      g_P[R * NN * D];    // bf16: x @ Rtop[r]
__device__ u16      g_Q[R * NN * D];    // bf16: x @ Rbot[r]
__device__ u16      g_xl[NN * D];       // bf16: x @ Wl + bl
__device__ u16      g_Wn[12 * D * D];   // bf16 transposed weights: Wl,Rtop[5],Rbot[5],We
__device__ int      g_cnt[NN];          // CSR: in-degree counts
__device__ int      g_cur[NN];          // CSR: scatter cursors
__device__ int      g_off[NN + 1];      // CSR: row offsets (by dst)
__device__ int      g_eidx[NE];         // CSR: edge ids sorted by dst

__global__ void k_cvt(const float* __restrict__ e) {
    int i = blockIdx.x * 256 + threadIdx.x;
    g_x[i] = e[i];
}

// ---- CSR build (edge list identical for both layers: build once) ----
__global__ void k_zcnt() {
    int i = blockIdx.x * 256 + threadIdx.x;   // NN threads
    g_cnt[i] = 0; g_cur[i] = 0;
}
__global__ void k_count(const int* __restrict__ ei) {
    int i = blockIdx.x * 256 + threadIdx.x;   // NE threads
    atomicAdd(&g_cnt[ei[NE + i]], 1);
}
__global__ void k_scan() {   // 1 block, 1024 threads, 32 elems each
    __shared__ int sums[1024];
    const int t = threadIdx.x;
    const int base = t * 32;
    int local[32];
    int s = 0;
#pragma unroll
    for (int i = 0; i < 32; ++i) { local[i] = s; s += g_cnt[base + i]; }
    sums[t] = s;
    __syncthreads();
    for (int off = 1; off < 1024; off <<= 1) {
        int v = (t >= off) ? sums[t - off] : 0;
        __syncthreads();
        sums[t] += v;
        __syncthreads();
    }
    int chunkoff = (t == 0) ? 0 : sums[t - 1];
#pragma unroll
    for (int i = 0; i < 32; ++i) g_off[base + i] = chunkoff + local[i];
    if (t == 1023) g_off[NN] = sums[1023];
}
__global__ void k_scatter(const int* __restrict__ ei) {
    int i = blockIdx.x * 256 + threadIdx.x;   // NE threads
    int d = ei[NE + i];
    int pos = atomicAdd(&g_cur[d], 1);
    g_eidx[g_off[d] + pos] = i;
}

// ---- transpose + bf16-cast all 12 weight matrices: Wt[n][k] = W[k][n] ----
__global__ void k_prep(const float* __restrict__ Wl, const float* __restrict__ Rm,
                       const float* __restrict__ We) {
    int i = blockIdx.x * 256 + threadIdx.x;   // source element
    int y = blockIdx.y;
    int k = i >> 7, n = i & 127;
    const float* src;
    if (y == 0) src = Wl;
    else if (y <= R) src = Rm + (size_t)(y - 1) * 2 * D * D;
    else if (y <= 2 * R) src = Rm + (size_t)(y - 1 - R) * 2 * D * D + D * D;
    else src = We;
    g_Wn[(size_t)y * D * D + n * D + k] = f2bs(src[i]);
}

// ---- node transforms (MFMA): xl / P[r] / Q[r] = x @ W (+ bias for xl) ----
// flat grid NN/64*11, XCD-swizzled so the 11 wsel-blocks of one x-tile share an XCD
__global__ __launch_bounds__(256) void k_node(const float* __restrict__ bl) {
    __shared__ __align__(16) short sX[64 * LW];
    __shared__ __align__(16) short sW[D * LW];
    const int tid = threadIdx.x;
    // swizzle: same x-tile -> same id%8 class (same XCD heuristic) across wsel
    const int id = blockIdx.x;
    const int slot = id & 7;
    const int rest = id >> 3;
    const int wsel = rest % 11;
    const int n0 = ((rest / 11) * 8 + slot) * 64;

#pragma unroll
    for (int i = 0; i < 16; ++i) {
        int flat = i * 256 + tid;
        int row = flat >> 6, cp = (flat & 63) << 1;
        const float2 v = *(const float2*)&g_x[(size_t)(n0 + row) * D + cp];
        ((u32*)sX)[row * (LW / 2) + (cp >> 1)] = pack2(v.x, v.y);
    }
    const u16* Wt = g_Wn + (size_t)wsel * D * D;
#pragma unroll
    for (int i = 0; i < 8; ++i) {
        int flat = i * 256 + tid;
        int n = flat >> 4, c8 = (flat & 15) << 3;
        *(uint4*)&sW[n * LW + c8] = *(const uint4*)&Wt[n * D + c8];
    }
    __syncthreads();

    const int l = tid & 63, w = tid >> 6;
    const int mrow = l & 15, quad = l >> 4;
    f4v acc[8];
#pragma unroll
    for (int nt = 0; nt < 8; ++nt) acc[nt] = (f4v){0.f, 0.f, 0.f, 0.f};
#pragma unroll
    for (int s = 0; s < 4; ++s) {
        s8v a = *(const s8v*)&sX[(w * 16 + mrow) * LW + s * 32 + quad * 8];
#pragma unroll
        for (int nt = 0; nt < 8; ++nt) {
            s8v b = *(const s8v*)&sW[(nt * 16 + mrow) * LW + s * 32 + quad * 8];
            acc[nt] = __builtin_amdgcn_mfma_f32_16x16x32_bf16(a, b, acc[nt], 0, 0, 0);
        }
    }

    u16* out = (wsel == 0) ? g_xl
             : (wsel <= R) ? g_P + (size_t)(wsel - 1) * NN * D
                           : g_Q + (size_t)(wsel - 1 - R) * NN * D;
#pragma unroll
    for (int nt = 0; nt < 8; ++nt) {
        int col = nt * 16 + mrow;
        float bias = (wsel == 0) ? bl[col] : 0.f;
#pragma unroll
        for (int r = 0; r < 4; ++r) {
            int row = n0 + w * 16 + quad * 4 + r;
            out[(size_t)row * D + col] = f2bs(acc[nt][r] + bias);
        }
    }
}

// ---- fused edge kernel (MFMA, CSR-ordered, direct A-frags, identity-B xl fold) ----
// block = 64 CSR positions (4 waves x 16 edges); logits -> g_araw[pos]
__global__ __launch_bounds__(256) void k_edge(
        const float* __restrict__ att, const int* __restrict__ ei,
        const int* __restrict__ et) {
    __shared__ __align__(16) short sWeT[D * LW];   // 34816 B
    __shared__ float als[64][H];
    __shared__ int es[64], ed[64], er[64];
    const int tid = threadIdx.x;
    const int e0 = blockIdx.x * 64;
    const u16* WeT = g_Wn + (size_t)11 * D * D;

    if (tid < 64) {
        int e = g_eidx[e0 + tid];
        es[tid] = ei[e];
        ed[tid] = ei[NE + e];
        er[tid] = et[e];
    }
#pragma unroll
    for (int i = 0; i < 8; ++i) {
        int flat = i * 256 + tid;
        int n = flat >> 4, c8 = (flat & 15) << 3;
        *(uint4*)&sWeT[n * LW + c8] = *(const uint4*)&WeT[n * D + c8];
    }
    __syncthreads();

    const int l = tid & 63, w = tid >> 6;
    const int mrow = l & 15, quad = l >> 4;
    const int myrow = w * 16 + mrow;

    // identity B-frags: Bev for even nt (k_local == mrow), Bod for odd (== mrow+16)
    union { u32 u[4]; s8v v; } bev, bod;
#pragma unroll
    for (int jp = 0; jp < 4; ++jp) {
        int j0 = quad * 8 + jp * 2, j1 = j0 + 1;
        bev.u[jp] = ((j0 == mrow) ? 0x3F80u : 0u) | ((j1 == mrow) ? 0x3F800000u : 0u);
        bod.u[jp] = ((j0 == mrow + 16) ? 0x3F80u : 0u) | ((j1 == mrow + 16) ? 0x3F800000u : 0u);
    }

    // A-fragments: ea = gelu(P[src]+Q[dst]); A' = bf16(xl[src]+xl[dst])
    const u16* Prow = g_P + ((size_t)er[myrow] * NN + es[myrow]) * D;
    const u16* Qrow = g_Q + ((size_t)er[myrow] * NN + ed[myrow]) * D;
    const u16* Xs = g_xl + (size_t)es[myrow] * D;
    const u16* Xd = g_xl + (size_t)ed[myrow] * D;
    union { u32 u[4]; s8v v; } af[4], xf[4];
#pragma unroll
    for (int s = 0; s < 4; ++s) {
        int c0 = s * 32 + quad * 8;
        uint4 pu = *(const uint4*)&Prow[c0];
        uint4 qu = *(const uint4*)&Qrow[c0];
        af[s].u[0] = pack2(gelu_f(bflo(pu.x) + bflo(qu.x)), gelu_f(bfhi(pu.x) + bfhi(qu.x)));
        af[s].u[1] = pack2(gelu_f(bflo(pu.y) + bflo(qu.y)), gelu_f(bfhi(pu.y) + bfhi(qu.y)));
        af[s].u[2] = pack2(gelu_f(bflo(pu.z) + bflo(qu.z)), gelu_f(bfhi(pu.z) + bfhi(qu.z)));
        af[s].u[3] = pack2(gelu_f(bflo(pu.w) + bflo(qu.w)), gelu_f(bfhi(pu.w) + bfhi(qu.w)));
        uint4 su = *(const uint4*)&Xs[c0];
        uint4 du = *(const uint4*)&Xd[c0];
        xf[s].u[0] = pack2(bflo(su.x) + bflo(du.x), bfhi(su.x) + bfhi(du.x));
        xf[s].u[1] = pack2(bflo(su.y) + bflo(du.y), bfhi(su.y) + bfhi(du.y));
        xf[s].u[2] = pack2(bflo(su.z) + bflo(du.z), bfhi(su.z) + bfhi(du.z));
        xf[s].u[3] = pack2(bflo(su.w) + bflo(du.w), bfhi(su.w) + bfhi(du.w));
    }

    f4v acc[8];
#pragma unroll
    for (int nt = 0; nt < 8; ++nt) acc[nt] = (f4v){0.f, 0.f, 0.f, 0.f};
#pragma unroll
    for (int s = 0; s < 4; ++s) {
#pragma unroll
        for (int nt = 0; nt < 8; ++nt) {
            s8v b = *(const s8v*)&sWeT[(nt * 16 + mrow) * LW + s * 32 + quad * 8];
            acc[nt] = __builtin_amdgcn_mfma_f32_16x16x32_bf16(af[s].v, b, acc[nt], 0, 0, 0);
        }
        // fold xl[src]+xl[dst] via identity-B: acc[nt] += A'[s] restricted to its cols
        acc[2 * s]     = __builtin_amdgcn_mfma_f32_16x16x32_bf16(xf[s].v, bev.v, acc[2 * s], 0, 0, 0);
        acc[2 * s + 1] = __builtin_amdgcn_mfma_f32_16x16x32_bf16(xf[s].v, bod.v, acc[2 * s + 1], 0, 0, 0);
    }

    // epilogue in C-layout: edge = w*16 + quad*4 + r, col = nt*16 + mrow
    float hsum[4][4];
#pragma unroll
    for (int r = 0; r < 4; ++r)
#pragma unroll
        for (int h = 0; h < 4; ++h) hsum[r][h] = 0.f;
#pragma unroll
    for (int nt = 0; nt < 8; ++nt) {
        int col = nt * 16 + mrow;
        float av = att[col];
        int h = nt >> 1;
#pragma unroll
        for (int r = 0; r < 4; ++r) {
            float m = acc[nt][r];
            float lr = m > 0.f ? m : 0.2f * m;
            hsum[r][h] = fmaf(lr, av, hsum[r][h]);
        }
    }
#pragma unroll
    for (int r = 0; r < 4; ++r)
#pragma unroll
        for (int h = 0; h < 4; ++h) {
            float v = hsum[r][h];
            v += __shfl_xor(v, 1); v += __shfl_xor(v, 2);
            v += __shfl_xor(v, 4); v += __shfl_xor(v, 8);
            hsum[r][h] = v;
        }
    if (mrow == 0) {
#pragma unroll
        for (int r = 0; r < 4; ++r)
#pragma unroll
            for (int h = 0; h < 4; ++h)
                als[w * 16 + quad * 4 + r][h] = hsum[r][h];
    }
    __syncthreads();

    {   // position-indexed logit store (coalesced; k_gath reads contiguously)
        int el = tid >> 2, h = tid & 3;
        g_araw[(size_t)(e0 + el) * H + h] = als[el][h];
    }
}

// ---- fused gather: per-dst softmax (max+denom) + aggregation + bias + act ----
// one wave per dst; block 256 = 4 dsts; grid NN/4
__global__ __launch_bounds__(256) void k_gath(const int* __restrict__ ei,
                                              const float* __restrict__ bias,
                                              int do_gelu) {
    const int lane = threadIdx.x & 63;
    const int d = blockIdx.x * 4 + (threadIdx.x >> 6);
    const int off = g_off[d];
    const int deg = g_off[d + 1] - off;
    const int h = lane >> 4;        // head for cols 2*lane, 2*lane+1
    const int slot = lane & 15;

    // per-head segment max (coalesced: araw is CSR-position indexed)
    float mx = -3.4e38f;
    for (int p = slot; p < deg; p += 16)
        mx = fmaxf(mx, g_araw[(size_t)(off + p) * H + h]);
    mx = fmaxf(mx, __shfl_xor(mx, 1));
    mx = fmaxf(mx, __shfl_xor(mx, 2));
    mx = fmaxf(mx, __shfl_xor(mx, 4));
    mx = fmaxf(mx, __shfl_xor(mx, 8));

    // per-head denom
    float den = 0.f;
    for (int p = slot; p < deg; p += 16)
        den += __expf(g_araw[(size_t)(off + p) * H + h] - mx);
    den += __shfl_xor(den, 1);
    den += __shfl_xor(den, 2);
    den += __shfl_xor(den, 4);
    den += __shfl_xor(den, 8);
    const float inv = 1.f / (den + 1e-16f);

    // aggregate: cols (2*lane, 2*lane+1)
    float a0 = 0.f, a1 = 0.f;
    for (int p = 0; p < deg; ++p) {
        int s = ei[g_eidx[off + p]];
        float cf = __expf(g_araw[(size_t)(off + p) * H + h] - mx) * inv;
        u32 w = *(const u32*)&g_xl[(size_t)s * D + lane * 2];
        a0 = fmaf(bflo(w), cf, a0);
        a1 = fmaf(bfhi(w), cf, a1);
    }
    float v0 = a0 + bias[lane * 2];
    float v1 = a1 + bias[lane * 2 + 1];
    if (do_gelu) { v0 = gelu_f(v0); v1 = gelu_f(v1); }
    *(float2*)&g_x[(size_t)d * D + lane * 2] = make_float2(v0, v1);
}

// ---- output head: y = x[:BS]@out_w + out_b ; LayerNorm(eps=1e-12) ----
__global__ void k_head(const float* __restrict__ ow, const float* __restrict__ ob,
                       const float* __restrict__ g, const float* __restrict__ b,
                       float* __restrict__ out) {
    __shared__ float xs[D];
    __shared__ float red[D];
    int j = threadIdx.x, row = blockIdx.x;
    xs[j] = g_x[(size_t)row * D + j];
    __syncthreads();
    float y = ob[j];
#pragma unroll 8
    for (int k = 0; k < D; ++k) y = fmaf(xs[k], ow[k * D + j], y);
    red[j] = y;
    __syncthreads();
    for (int s = 64; s > 0; s >>= 1) { if (j < s) red[j] += red[j + s]; __syncthreads(); }
    float mu = red[0] * (1.f / D);
    __syncthreads();
    float dv = y - mu;
    red[j] = dv * dv;
    __syncthreads();
    for (int s = 64; s > 0; s >>= 1) { if (j < s) red[j] += red[j + s]; __syncthreads(); }
    float var = red[0] * (1.f / D);
    out[(size_t)row * D + j] = dv * rsqrtf(var + 1e-12f) * g[j] + b[j];
}

extern "C" void kernel_launch(void* const* d_in, const int* in_sizes, int n_in,
                              void* d_out, int out_size, void* d_ws, size_t ws_size,
                              hipStream_t stream) {
    (void)in_sizes; (void)n_in; (void)out_size; (void)d_ws; (void)ws_size;
    const float* embs = (const float*)d_in[0];
    const int*   ei   = (const int*)d_in[1];
    const int*   et   = (const int*)d_in[2];
    const float* rel  = (const float*)d_in[3];
    const float* wl[2]   = { (const float*)d_in[4],  (const float*)d_in[9]  };
    const float* bl[2]   = { (const float*)d_in[5],  (const float*)d_in[10] };
    const float* we[2]   = { (const float*)d_in[6],  (const float*)d_in[11] };
    const float* attw[2] = { (const float*)d_in[7],  (const float*)d_in[12] };
    const float* bs[2]   = { (const float*)d_in[8],  (const float*)d_in[13] };
    const float* ow  = (const float*)d_in[14];
    const float* ob  = (const float*)d_in[15];
    const float* lng = (const float*)d_in[16];
    const float* lnb = (const float*)d_in[17];
    float* out = (float*)d_out;

    k_cvt<<<NN * D / 256, 256, 0, stream>>>(embs);

    // CSR by dst (edge list shared by both layers)
    k_zcnt<<<NN / 256, 256, 0, stream>>>();
    k_count<<<NE / 256, 256, 0, stream>>>(ei);
    k_scan<<<1, 1024, 0, stream>>>();
    k_scatter<<<NE / 256, 256, 0, stream>>>(ei);

    for (int l = 0; l < 2; ++l) {
        const float* Rm = rel + (size_t)l * R * 2 * D * D;
        k_prep<<<dim3(D * D / 256, 12), 256, 0, stream>>>(wl[l], Rm, we[l]);
        k_node<<<(NN / 64) * 11, 256, 0, stream>>>(bl[l]);
        k_edge<<<NE / 64, 256, 0, stream>>>(attw[l], ei, et);
        k_gath<<<NN / 4, 256, 0, stream>>>(ei, bs[l], l == 0 ? 1 : 0);
    }

    k_head<<<BS, 128, 0, stream>>>(ow, ob, lng, lnb, out);
}

// Round 9
// 568.764 us; speedup vs baseline: 5.7784x; 1.1861x over previous
//
#include <hip/hip_runtime.h>
#include <hip/hip_bf16.h>

typedef __hip_bfloat16 bf16;
typedef __attribute__((ext_vector_type(8))) short s8v;
typedef __attribute__((ext_vector_type(4))) float f4v;
typedef unsigned short u16;
typedef unsigned int u32;

#define NN 32768
#define NE 524288
#define D 128
#define H 4
#define C 32
#define R 5
#define BS 8192
#define LW 136   // padded LDS row stride (bf16 elems)

__device__ __forceinline__ float b2f(bf16 x) { return __bfloat162float(x); }
__device__ __forceinline__ bf16 f2b(float x) { return __float2bfloat16(x); }
__device__ __forceinline__ u16 f2bs(float x) { bf16 h = f2b(x); return *(u16*)&h; }
__device__ __forceinline__ float us2f(u16 u) { return __uint_as_float(((u32)u) << 16); }
__device__ __forceinline__ float bflo(u32 u) { return __uint_as_float(u << 16); }
__device__ __forceinline__ float bfhi(u32 u) { return __uint_as_float(u & 0xffff0000u); }
__device__ __forceinline__ u32 pack2(float a, float b) {
    return (u32)f2bs(a) | ((u32)f2bs(b) << 16);
}
__device__ __forceinline__ float gelu_f(float x) {   // exact (epilogue use)
    return 0.5f * x * (1.f + erff(x * 0.7071067811865475f));
}
// fast gelu: x * sigmoid(2*sqrt(2/pi)*(x + 0.044715 x^3)); |err| < ~1e-3
__device__ __forceinline__ float gelu_fast(float x) {
    float x2 = x * x;
    float u = x * fmaf(0.0713548162f, x2, 1.5957691216f);
    return x / (1.f + __expf(-u));
}

// ---- static device scratch ----
__device__ float    g_x[NN * D];        // f32 working activations
__device__ float    g_araw[NE * H];     // attention logits, CSR-position indexed
__device__ u16      g_P[R * NN * D];    // bf16: x @ Rtop[r]
__device__ u16      g_Q[R * NN * D];    // bf16: x @ Rbot[r]
__device__ u16      g_xl[NN * D];       // bf16: x @ Wl + bl
__device__ u16      g_Wn[12 * D * D];   // bf16 transposed weights: Wl,Rtop[5],Rbot[5],We
__device__ int      g_cnt[NN];          // CSR: in-degree counts
__device__ int      g_cur[NN];          // CSR: scatter cursors
__device__ int      g_off[NN + 1];      // CSR: row offsets (by dst)
__device__ int      g_se[NE];           // CSR-ordered src node ids
__device__ int      g_de[NE];           // CSR-ordered dst node ids
__device__ int      g_re[NE];           // CSR-ordered relation ids

__global__ void k_cvt(const float* __restrict__ e) {
    int i = blockIdx.x * 256 + threadIdx.x;
    g_x[i] = e[i];
}

// ---- CSR build (edge list identical for both layers: build once) ----
__global__ void k_zcnt() {
    int i = blockIdx.x * 256 + threadIdx.x;   // NN threads
    g_cnt[i] = 0; g_cur[i] = 0;
}
__global__ void k_count(const int* __restrict__ ei) {
    int i = blockIdx.x * 256 + threadIdx.x;   // NE threads
    atomicAdd(&g_cnt[ei[NE + i]], 1);
}
__global__ void k_scan() {   // 1 block, 1024 threads, 32 elems each
    __shared__ int sums[1024];
    const int t = threadIdx.x;
    const int base = t * 32;
    int local[32];
    int s = 0;
#pragma unroll
    for (int i = 0; i < 32; ++i) { local[i] = s; s += g_cnt[base + i]; }
    sums[t] = s;
    __syncthreads();
    for (int off = 1; off < 1024; off <<= 1) {
        int v = (t >= off) ? sums[t - off] : 0;
        __syncthreads();
        sums[t] += v;
        __syncthreads();
    }
    int chunkoff = (t == 0) ? 0 : sums[t - 1];
#pragma unroll
    for (int i = 0; i < 32; ++i) g_off[base + i] = chunkoff + local[i];
    if (t == 1023) g_off[NN] = sums[1023];
}
__global__ void k_scatter(const int* __restrict__ ei, const int* __restrict__ et) {
    int i = blockIdx.x * 256 + threadIdx.x;   // NE threads
    int d = ei[NE + i];
    int pos = g_off[d] + atomicAdd(&g_cur[d], 1);
    g_se[pos] = ei[i];
    g_de[pos] = d;
    g_re[pos] = et[i];
}

// ---- transpose + bf16-cast all 12 weight matrices: Wt[n][k] = W[k][n] ----
__global__ void k_prep(const float* __restrict__ Wl, const float* __restrict__ Rm,
                       const float* __restrict__ We) {
    int i = blockIdx.x * 256 + threadIdx.x;   // source element
    int y = blockIdx.y;
    int k = i >> 7, n = i & 127;
    const float* src;
    if (y == 0) src = Wl;
    else if (y <= R) src = Rm + (size_t)(y - 1) * 2 * D * D;
    else if (y <= 2 * R) src = Rm + (size_t)(y - 1 - R) * 2 * D * D + D * D;
    else src = We;
    g_Wn[(size_t)y * D * D + n * D + k] = f2bs(src[i]);
}

// ---- node transforms (MFMA): xl / P[r] / Q[r] = x @ W (+ bias for xl) ----
__global__ __launch_bounds__(256) void k_node(const float* __restrict__ bl) {
    __shared__ __align__(16) short sX[64 * LW];
    __shared__ __align__(16) short sW[D * LW];
    const int tid = threadIdx.x;
    const int id = blockIdx.x;
    const int slot = id & 7;
    const int rest = id >> 3;
    const int wsel = rest % 11;
    const int n0 = ((rest / 11) * 8 + slot) * 64;

#pragma unroll
    for (int i = 0; i < 16; ++i) {
        int flat = i * 256 + tid;
        int row = flat >> 6, cp = (flat & 63) << 1;
        const float2 v = *(const float2*)&g_x[(size_t)(n0 + row) * D + cp];
        ((u32*)sX)[row * (LW / 2) + (cp >> 1)] = pack2(v.x, v.y);
    }
    const u16* Wt = g_Wn + (size_t)wsel * D * D;
#pragma unroll
    for (int i = 0; i < 8; ++i) {
        int flat = i * 256 + tid;
        int n = flat >> 4, c8 = (flat & 15) << 3;
        *(uint4*)&sW[n * LW + c8] = *(const uint4*)&Wt[n * D + c8];
    }
    __syncthreads();

    const int l = tid & 63, w = tid >> 6;
    const int mrow = l & 15, quad = l >> 4;
    f4v acc[8];
#pragma unroll
    for (int nt = 0; nt < 8; ++nt) acc[nt] = (f4v){0.f, 0.f, 0.f, 0.f};
#pragma unroll
    for (int s = 0; s < 4; ++s) {
        s8v a = *(const s8v*)&sX[(w * 16 + mrow) * LW + s * 32 + quad * 8];
#pragma unroll
        for (int nt = 0; nt < 8; ++nt) {
            s8v b = *(const s8v*)&sW[(nt * 16 + mrow) * LW + s * 32 + quad * 8];
            acc[nt] = __builtin_amdgcn_mfma_f32_16x16x32_bf16(a, b, acc[nt], 0, 0, 0);
        }
    }

    u16* out = (wsel == 0) ? g_xl
             : (wsel <= R) ? g_P + (size_t)(wsel - 1) * NN * D
                           : g_Q + (size_t)(wsel - 1 - R) * NN * D;
#pragma unroll
    for (int nt = 0; nt < 8; ++nt) {
        int col = nt * 16 + mrow;
        float bias = (wsel == 0) ? bl[col] : 0.f;
#pragma unroll
        for (int r = 0; r < 4; ++r) {
            int row = n0 + w * 16 + quad * 4 + r;
            out[(size_t)row * D + col] = f2bs(acc[nt][r] + bias);
        }
    }
}

// ---- fused edge kernel (MFMA, CSR-ordered, direct A-frags, identity-B xl fold) ----
__global__ __launch_bounds__(256) void k_edge(const float* __restrict__ att) {
    __shared__ __align__(16) short sWeT[D * LW];   // 34816 B
    __shared__ float als[64][H];
    __shared__ int es[64], ed[64], er[64];
    const int tid = threadIdx.x;
    const int e0 = blockIdx.x * 64;
    const u16* WeT = g_Wn + (size_t)11 * D * D;

    if (tid < 64) {   // fully coalesced CSR-ordered metadata
        es[tid] = g_se[e0 + tid];
        ed[tid] = g_de[e0 + tid];
        er[tid] = g_re[e0 + tid];
    }
#pragma unroll
    for (int i = 0; i < 8; ++i) {
        int flat = i * 256 + tid;
        int n = flat >> 4, c8 = (flat & 15) << 3;
        *(uint4*)&sWeT[n * LW + c8] = *(const uint4*)&WeT[n * D + c8];
    }
    __syncthreads();

    const int l = tid & 63, w = tid >> 6;
    const int mrow = l & 15, quad = l >> 4;
    const int myrow = w * 16 + mrow;

    // identity B-frags: Bev for even nt (k_local == mrow), Bod for odd (== mrow+16)
    union { u32 u[4]; s8v v; } bev, bod;
#pragma unroll
    for (int jp = 0; jp < 4; ++jp) {
        int j0 = quad * 8 + jp * 2, j1 = j0 + 1;
        bev.u[jp] = ((j0 == mrow) ? 0x3F80u : 0u) | ((j1 == mrow) ? 0x3F800000u : 0u);
        bod.u[jp] = ((j0 == mrow + 16) ? 0x3F80u : 0u) | ((j1 == mrow + 16) ? 0x3F800000u : 0u);
    }

    const u16* Prow = g_P + ((size_t)er[myrow] * NN + es[myrow]) * D;
    const u16* Qrow = g_Q + ((size_t)er[myrow] * NN + ed[myrow]) * D;
    const u16* Xs = g_xl + (size_t)es[myrow] * D;
    const u16* Xd = g_xl + (size_t)ed[myrow] * D;
    union { u32 u[4]; s8v v; } af[4], xf[4];
#pragma unroll
    for (int s = 0; s < 4; ++s) {
        int c0 = s * 32 + quad * 8;
        uint4 pu = *(const uint4*)&Prow[c0];
        uint4 qu = *(const uint4*)&Qrow[c0];
        af[s].u[0] = pack2(gelu_fast(bflo(pu.x) + bflo(qu.x)), gelu_fast(bfhi(pu.x) + bfhi(qu.x)));
        af[s].u[1] = pack2(gelu_fast(bflo(pu.y) + bflo(qu.y)), gelu_fast(bfhi(pu.y) + bfhi(qu.y)));
        af[s].u[2] = pack2(gelu_fast(bflo(pu.z) + bflo(qu.z)), gelu_fast(bfhi(pu.z) + bfhi(qu.z)));
        af[s].u[3] = pack2(gelu_fast(bflo(pu.w) + bflo(qu.w)), gelu_fast(bfhi(pu.w) + bfhi(qu.w)));
        uint4 su = *(const uint4*)&Xs[c0];
        uint4 du = *(const uint4*)&Xd[c0];
        xf[s].u[0] = pack2(bflo(su.x) + bflo(du.x), bfhi(su.x) + bfhi(du.x));
        xf[s].u[1] = pack2(bflo(su.y) + bflo(du.y), bfhi(su.y) + bfhi(du.y));
        xf[s].u[2] = pack2(bflo(su.z) + bflo(du.z), bfhi(su.z) + bfhi(du.z));
        xf[s].u[3] = pack2(bflo(su.w) + bflo(du.w), bfhi(su.w) + bfhi(du.w));
    }

    f4v acc[8];
#pragma unroll
    for (int nt = 0; nt < 8; ++nt) acc[nt] = (f4v){0.f, 0.f, 0.f, 0.f};
#pragma unroll
    for (int s = 0; s < 4; ++s) {
#pragma unroll
        for (int nt = 0; nt < 8; ++nt) {
            s8v b = *(const s8v*)&sWeT[(nt * 16 + mrow) * LW + s * 32 + quad * 8];
            acc[nt] = __builtin_amdgcn_mfma_f32_16x16x32_bf16(af[s].v, b, acc[nt], 0, 0, 0);
        }
        acc[2 * s]     = __builtin_amdgcn_mfma_f32_16x16x32_bf16(xf[s].v, bev.v, acc[2 * s], 0, 0, 0);
        acc[2 * s + 1] = __builtin_amdgcn_mfma_f32_16x16x32_bf16(xf[s].v, bod.v, acc[2 * s + 1], 0, 0, 0);
    }

    // epilogue in C-layout: edge = w*16 + quad*4 + r, col = nt*16 + mrow
    float hsum[4][4];
#pragma unroll
    for (int r = 0; r < 4; ++r)
#pragma unroll
        for (int h = 0; h < 4; ++h) hsum[r][h] = 0.f;
#pragma unroll
    for (int nt = 0; nt < 8; ++nt) {
        int col = nt * 16 + mrow;
        float av = att[col];
        int h = nt >> 1;
#pragma unroll
        for (int r = 0; r < 4; ++r) {
            float m = acc[nt][r];
            float lr = m > 0.f ? m : 0.2f * m;
            hsum[r][h] = fmaf(lr, av, hsum[r][h]);
        }
    }
#pragma unroll
    for (int r = 0; r < 4; ++r)
#pragma unroll
        for (int h = 0; h < 4; ++h) {
            float v = hsum[r][h];
            v += __shfl_xor(v, 1); v += __shfl_xor(v, 2);
            v += __shfl_xor(v, 4); v += __shfl_xor(v, 8);
            hsum[r][h] = v;
        }
    if (mrow == 0) {
#pragma unroll
        for (int r = 0; r < 4; ++r)
#pragma unroll
            for (int h = 0; h < 4; ++h)
                als[w * 16 + quad * 4 + r][h] = hsum[r][h];
    }
    __syncthreads();

    {
        int el = tid >> 2, h = tid & 3;
        g_araw[(size_t)(e0 + el) * H + h] = als[el][h];
    }
}

// ---- fused gather: per-dst softmax (max+denom) + aggregation + bias + act ----
// one wave per dst; block 256 = 4 dsts; grid NN/4
__global__ __launch_bounds__(256) void k_gath(const float* __restrict__ bias,
                                              int do_gelu) {
    const int lane = threadIdx.x & 63;
    const int d = blockIdx.x * 4 + (threadIdx.x >> 6);
    const int off = g_off[d];
    const int deg = g_off[d + 1] - off;
    const int h = lane >> 4;        // head for cols 2*lane, 2*lane+1
    const int slot = lane & 15;

    // per-head segment max (coalesced: araw is CSR-position indexed)
    float mx = -3.4e38f;
    for (int p = slot; p < deg; p += 16)
        mx = fmaxf(mx, g_araw[(size_t)(off + p) * H + h]);
    mx = fmaxf(mx, __shfl_xor(mx, 1));
    mx = fmaxf(mx, __shfl_xor(mx, 2));
    mx = fmaxf(mx, __shfl_xor(mx, 4));
    mx = fmaxf(mx, __shfl_xor(mx, 8));

    // per-head denom
    float den = 0.f;
    for (int p = slot; p < deg; p += 16)
        den += __expf(g_araw[(size_t)(off + p) * H + h] - mx);
    den += __shfl_xor(den, 1);
    den += __shfl_xor(den, 2);
    den += __shfl_xor(den, 4);
    den += __shfl_xor(den, 8);
    const float inv = 1.f / (den + 1e-16f);

    // aggregate: cols (2*lane, 2*lane+1); 4-wide unrolled so loads pipeline
    const int* __restrict__ srcs = g_se + off;
    float a0 = 0.f, a1 = 0.f;
    int p = 0;
    for (; p + 4 <= deg; p += 4) {
        int s0 = srcs[p], s1 = srcs[p + 1], s2 = srcs[p + 2], s3 = srcs[p + 3];
        u32 w0 = *(const u32*)&g_xl[(size_t)s0 * D + lane * 2];
        u32 w1 = *(const u32*)&g_xl[(size_t)s1 * D + lane * 2];
        u32 w2 = *(const u32*)&g_xl[(size_t)s2 * D + lane * 2];
        u32 w3 = *(const u32*)&g_xl[(size_t)s3 * D + lane * 2];
        float c0 = __expf(g_araw[(size_t)(off + p) * H + h] - mx) * inv;
        float c1 = __expf(g_araw[(size_t)(off + p + 1) * H + h] - mx) * inv;
        float c2 = __expf(g_araw[(size_t)(off + p + 2) * H + h] - mx) * inv;
        float c3 = __expf(g_araw[(size_t)(off + p + 3) * H + h] - mx) * inv;
        a0 = fmaf(bflo(w0), c0, a0); a1 = fmaf(bfhi(w0), c0, a1);
        a0 = fmaf(bflo(w1), c1, a0); a1 = fmaf(bfhi(w1), c1, a1);
        a0 = fmaf(bflo(w2), c2, a0); a1 = fmaf(bfhi(w2), c2, a1);
        a0 = fmaf(bflo(w3), c3, a0); a1 = fmaf(bfhi(w3), c3, a1);
    }
    for (; p < deg; ++p) {
        int s = srcs[p];
        float cf = __expf(g_araw[(size_t)(off + p) * H + h] - mx) * inv;
        u32 w = *(const u32*)&g_xl[(size_t)s * D + lane * 2];
        a0 = fmaf(bflo(w), cf, a0);
        a1 = fmaf(bfhi(w), cf, a1);
    }
    float v0 = a0 + bias[lane * 2];
    float v1 = a1 + bias[lane * 2 + 1];
    if (do_gelu) { v0 = gelu_f(v0); v1 = gelu_f(v1); }
    *(float2*)&g_x[(size_t)d * D + lane * 2] = make_float2(v0, v1);
}

// ---- output head: y = x[:BS]@out_w + out_b ; LayerNorm(eps=1e-12) ----
__global__ void k_head(const float* __restrict__ ow, const float* __restrict__ ob,
                       const float* __restrict__ g, const float* __restrict__ b,
                       float* __restrict__ out) {
    __shared__ float xs[D];
    __shared__ float red[D];
    int j = threadIdx.x, row = blockIdx.x;
    xs[j] = g_x[(size_t)row * D + j];
    __syncthreads();
    float y = ob[j];
#pragma unroll 8
    for (int k = 0; k < D; ++k) y = fmaf(xs[k], ow[k * D + j], y);
    red[j] = y;
    __syncthreads();
    for (int s = 64; s > 0; s >>= 1) { if (j < s) red[j] += red[j + s]; __syncthreads(); }
    float mu = red[0] * (1.f / D);
    __syncthreads();
    float dv = y - mu;
    red[j] = dv * dv;
    __syncthreads();
    for (int s = 64; s > 0; s >>= 1) { if (j < s) red[j] += red[j + s]; __syncthreads(); }
    float var = red[0] * (1.f / D);
    out[(size_t)row * D + j] = dv * rsqrtf(var + 1e-12f) * g[j] + b[j];
}

extern "C" void kernel_launch(void* const* d_in, const int* in_sizes, int n_in,
                              void* d_out, int out_size, void* d_ws, size_t ws_size,
                              hipStream_t stream) {
    (void)in_sizes; (void)n_in; (void)out_size; (void)d_ws; (void)ws_size;
    const float* embs = (const float*)d_in[0];
    const int*   ei   = (const int*)d_in[1];
    const int*   et   = (const int*)d_in[2];
    const float* rel  = (const float*)d_in[3];
    const float* wl[2]   = { (const float*)d_in[4],  (const float*)d_in[9]  };
    const float* bl[2]   = { (const float*)d_in[5],  (const float*)d_in[10] };
    const float* we[2]   = { (const float*)d_in[6],  (const float*)d_in[11] };
    const float* attw[2] = { (const float*)d_in[7],  (const float*)d_in[12] };
    const float* bs[2]   = { (const float*)d_in[8],  (const float*)d_in[13] };
    const float* ow  = (const float*)d_in[14];
    const float* ob  = (const float*)d_in[15];
    const float* lng = (const float*)d_in[16];
    const float* lnb = (const float*)d_in[17];
    float* out = (float*)d_out;

    k_cvt<<<NN * D / 256, 256, 0, stream>>>(embs);

    // CSR by dst (edge list shared by both layers)
    k_zcnt<<<NN / 256, 256, 0, stream>>>();
    k_count<<<NE / 256, 256, 0, stream>>>(ei);
    k_scan<<<1, 1024, 0, stream>>>();
    k_scatter<<<NE / 256, 256, 0, stream>>>(ei, et);

    for (int l = 0; l < 2; ++l) {
        const float* Rm = rel + (size_t)l * R * 2 * D * D;
        k_prep<<<dim3(D * D / 256, 12), 256, 0, stream>>>(wl[l], Rm, we[l]);
        k_node<<<(NN / 64) * 11, 256, 0, stream>>>(bl[l]);
        k_edge<<<NE / 64, 256, 0, stream>>>(attw[l]);
        k_gath<<<NN / 4, 256, 0, stream>>>(bs[l], l == 0 ? 1 : 0);
    }

    k_head<<<BS, 128, 0, stream>>>(ow, ob, lng, lnb, out);
}

// Round 10
// 545.576 us; speedup vs baseline: 6.0240x; 1.0425x over previous
//
#include <hip/hip_runtime.h>
#include <hip/hip_bf16.h>

typedef __hip_bfloat16 bf16;
typedef __attribute__((ext_vector_type(8))) short s8v;
typedef __attribute__((ext_vector_type(4))) float f4v;
typedef unsigned short u16;
typedef unsigned int u32;

#define NN 32768
#define NE 524288
#define D 128
#define H 4
#define C 32
#define R 5
#define BS 8192

__device__ __forceinline__ float b2f(bf16 x) { return __bfloat162float(x); }
__device__ __forceinline__ bf16 f2b(float x) { return __float2bfloat16(x); }
__device__ __forceinline__ u16 f2bs(float x) { bf16 h = f2b(x); return *(u16*)&h; }
__device__ __forceinline__ float us2f(u16 u) { return __uint_as_float(((u32)u) << 16); }
__device__ __forceinline__ float bflo(u32 u) { return __uint_as_float(u << 16); }
__device__ __forceinline__ float bfhi(u32 u) { return __uint_as_float(u & 0xffff0000u); }
// fast bf16 pair pack: round-half-up (+0x8000) then byte-perm; 3 VALU instrs
__device__ __forceinline__ u32 pack2r(float a, float b) {
    u32 ua = __float_as_uint(a) + 0x8000u;
    u32 ub = __float_as_uint(b) + 0x8000u;
    return __builtin_amdgcn_perm(ub, ua, 0x07060302u);   // lo16=hi(a), hi16=hi(b)
}
__device__ __forceinline__ u16 rnd16(float a) {
    return (u16)((__float_as_uint(a) + 0x8000u) >> 16);
}
__device__ __forceinline__ float gelu_f(float x) {   // exact (epilogue use)
    return 0.5f * x * (1.f + erff(x * 0.7071067811865475f));
}
// fast gelu: x * sigmoid(2*sqrt(2/pi)*(x + 0.044715 x^3)); |err| < ~1e-3
__device__ __forceinline__ float gelu_fast(float x) {
    float x2 = x * x;
    float u = x * fmaf(0.0713548162f, x2, 1.5957691216f);
    return x / (1.f + __expf(-u));
}

// ---- static device scratch ----
__device__ float    g_x[NN * D];         // f32 working activations
__device__ float    g_araw[NE * H];      // attention logits, CSR-position indexed
__device__ u16      g_P[R * NN * D];     // bf16: x @ Rtop[r]
__device__ u16      g_Q[R * NN * D];     // bf16: x @ Rbot[r]
__device__ u16      g_xl[NN * D];        // bf16: x @ Wl + bl
__device__ u16      g_WnF[13 * 2048 * 8];// bf16 weights in MFMA B-frag order:
                                         // Wl,Rtop[5],Rbot[5],We,OwT
__device__ int      g_cnt[NN];           // CSR: in-degree counts
__device__ int      g_cur[NN];           // CSR: scatter cursors
__device__ int      g_off[NN + 1];       // CSR: row offsets (by dst)
__device__ int      g_se[NE];            // CSR-ordered src node ids
__device__ int      g_de[NE];            // CSR-ordered dst node ids
__device__ int      g_re[NE];            // CSR-ordered relation ids

__global__ void k_cvt(const float* __restrict__ e) {
    int i = blockIdx.x * 256 + threadIdx.x;
    g_x[i] = e[i];
}

// ---- CSR build (edge list identical for both layers: build once) ----
__global__ void k_zcnt() {
    int i = blockIdx.x * 256 + threadIdx.x;   // NN threads
    g_cnt[i] = 0; g_cur[i] = 0;
}
__global__ void k_count(const int* __restrict__ ei) {
    int i = blockIdx.x * 256 + threadIdx.x;   // NE threads
    atomicAdd(&g_cnt[ei[NE + i]], 1);
}
__global__ void k_scan() {   // 1 block, 1024 threads, 32 elems each
    __shared__ int sums[1024];
    const int t = threadIdx.x;
    const int base = t * 32;
    int local[32];
    int s = 0;
#pragma unroll
    for (int i = 0; i < 32; ++i) { local[i] = s; s += g_cnt[base + i]; }
    sums[t] = s;
    __syncthreads();
    for (int off = 1; off < 1024; off <<= 1) {
        int v = (t >= off) ? sums[t - off] : 0;
        __syncthreads();
        sums[t] += v;
        __syncthreads();
    }
    int chunkoff = (t == 0) ? 0 : sums[t - 1];
#pragma unroll
    for (int i = 0; i < 32; ++i) g_off[base + i] = chunkoff + local[i];
    if (t == 1023) g_off[NN] = sums[1023];
}
__global__ void k_scatter(const int* __restrict__ ei, const int* __restrict__ et) {
    int i = blockIdx.x * 256 + threadIdx.x;   // NE threads
    int d = ei[NE + i];
    int pos = g_off[d] + atomicAdd(&g_cur[d], 1);
    g_se[pos] = ei[i];
    g_de[pos] = d;
    g_re[pos] = et[i];
}

// ---- weights -> bf16 MFMA B-fragment order ----
// frag f = (s*8+nt)*64+lane holds WeT[n=nt*16+(lane&15)][k=s*32+(lane>>4)*8 + 0..7]
// grid: (2048/256, 13)
__global__ void k_prep(const float* __restrict__ Wl, const float* __restrict__ Rm,
                       const float* __restrict__ We, const float* __restrict__ Ow) {
    int f = blockIdx.x * 256 + threadIdx.x;   // frag id 0..2047
    int y = blockIdx.y;
    const float* src;
    if (y == 0) src = Wl;
    else if (y <= R) src = Rm + (size_t)(y - 1) * 2 * D * D;
    else if (y <= 2 * R) src = Rm + (size_t)(y - 1 - R) * 2 * D * D + D * D;
    else if (y == 11) src = We;
    else src = Ow;
    int lane = f & 63, nt = (f >> 6) & 7, s = f >> 9;
    int n = nt * 16 + (lane & 15);
    int ks = s * 32 + (lane >> 4) * 8;
    u16 tmp[8];
#pragma unroll
    for (int j = 0; j < 8; ++j) tmp[j] = f2bs(src[(size_t)(ks + j) * D + n]);
    *(uint4*)&g_WnF[((size_t)y * 2048 + f) * 8] = *(uint4*)tmp;
}

// ---- node transforms (MFMA, LDS-free): xl / P[r] / Q[r] = x @ W (+ bias for xl) ----
// grid (NN/64, 11), block 256 (4 waves x 16-node tiles)
__global__ __launch_bounds__(256) void k_node(const float* __restrict__ bl) {
    const int tid = threadIdx.x;
    const int n0 = blockIdx.x * 64;
    const int wsel = blockIdx.y;
    const int l = tid & 63, w = tid >> 6;
    const int mrow = l & 15, quad = l >> 4;
    const float* xrow = g_x + (size_t)(n0 + w * 16 + mrow) * D;
    const u16* BF = g_WnF + (size_t)wsel * 2048 * 8;

    f4v acc[8];
#pragma unroll
    for (int nt = 0; nt < 8; ++nt) acc[nt] = (f4v){0.f, 0.f, 0.f, 0.f};
#pragma unroll
    for (int s = 0; s < 4; ++s) {
        int c0 = s * 32 + quad * 8;
        float4 xa = *(const float4*)&xrow[c0];
        float4 xb = *(const float4*)&xrow[c0 + 4];
        union { u32 u[4]; s8v v; } a;
        a.u[0] = pack2r(xa.x, xa.y);
        a.u[1] = pack2r(xa.z, xa.w);
        a.u[2] = pack2r(xb.x, xb.y);
        a.u[3] = pack2r(xb.z, xb.w);
#pragma unroll
        for (int nt = 0; nt < 8; ++nt) {
            s8v b = *(const s8v*)&BF[(size_t)((s * 8 + nt) * 64 + l) * 8];
            acc[nt] = __builtin_amdgcn_mfma_f32_16x16x32_bf16(a.v, b, acc[nt], 0, 0, 0);
        }
    }

    u16* out = (wsel == 0) ? g_xl
             : (wsel <= R) ? g_P + (size_t)(wsel - 1) * NN * D
                           : g_Q + (size_t)(wsel - 1 - R) * NN * D;
#pragma unroll
    for (int nt = 0; nt < 8; ++nt) {
        int col = nt * 16 + mrow;
        float bias = (wsel == 0) ? bl[col] : 0.f;
#pragma unroll
        for (int r = 0; r < 4; ++r) {
            int row = n0 + w * 16 + quad * 4 + r;
            out[(size_t)row * D + col] = rnd16(acc[nt][r] + bias);
        }
    }
}

// ---- fused edge kernel (MFMA, CSR-ordered, all operands direct, B from L2) ----
__global__ __launch_bounds__(256) void k_edge(const float* __restrict__ att) {
    __shared__ float als[64][H];
    const int tid = threadIdx.x;
    const int e0 = blockIdx.x * 64;
    const int l = tid & 63, w = tid >> 6;
    const int mrow = l & 15, quad = l >> 4;
    const int myrow = w * 16 + mrow;
    const u16* BF = g_WnF + (size_t)11 * 2048 * 8;

    const int se = g_se[e0 + myrow];
    const int de = g_de[e0 + myrow];
    const int re = g_re[e0 + myrow];

    // identity B-frags: Bev for even nt (k_local == mrow), Bod for odd (== mrow+16)
    union { u32 u[4]; s8v v; } bev, bod;
#pragma unroll
    for (int jp = 0; jp < 4; ++jp) {
        int j0 = quad * 8 + jp * 2, j1 = j0 + 1;
        bev.u[jp] = ((j0 == mrow) ? 0x3F80u : 0u) | ((j1 == mrow) ? 0x3F800000u : 0u);
        bod.u[jp] = ((j0 == mrow + 16) ? 0x3F80u : 0u) | ((j1 == mrow + 16) ? 0x3F800000u : 0u);
    }

    const u16* Prow = g_P + ((size_t)re * NN + se) * D;
    const u16* Qrow = g_Q + ((size_t)re * NN + de) * D;
    const u16* Xs = g_xl + (size_t)se * D;
    const u16* Xd = g_xl + (size_t)de * D;
    union { u32 u[4]; s8v v; } af[4], xf[4];
#pragma unroll
    for (int s = 0; s < 4; ++s) {
        int c0 = s * 32 + quad * 8;
        uint4 pu = *(const uint4*)&Prow[c0];
        uint4 qu = *(const uint4*)&Qrow[c0];
        af[s].u[0] = pack2r(gelu_fast(bflo(pu.x) + bflo(qu.x)), gelu_fast(bfhi(pu.x) + bfhi(qu.x)));
        af[s].u[1] = pack2r(gelu_fast(bflo(pu.y) + bflo(qu.y)), gelu_fast(bfhi(pu.y) + bfhi(qu.y)));
        af[s].u[2] = pack2r(gelu_fast(bflo(pu.z) + bflo(qu.z)), gelu_fast(bfhi(pu.z) + bfhi(qu.z)));
        af[s].u[3] = pack2r(gelu_fast(bflo(pu.w) + bflo(qu.w)), gelu_fast(bfhi(pu.w) + bfhi(qu.w)));
        uint4 su = *(const uint4*)&Xs[c0];
        uint4 du = *(const uint4*)&Xd[c0];
        xf[s].u[0] = pack2r(bflo(su.x) + bflo(du.x), bfhi(su.x) + bfhi(du.x));
        xf[s].u[1] = pack2r(bflo(su.y) + bflo(du.y), bfhi(su.y) + bfhi(du.y));
        xf[s].u[2] = pack2r(bflo(su.z) + bflo(du.z), bfhi(su.z) + bfhi(du.z));
        xf[s].u[3] = pack2r(bflo(su.w) + bflo(du.w), bfhi(su.w) + bfhi(du.w));
    }

    f4v acc[8];
#pragma unroll
    for (int nt = 0; nt < 8; ++nt) acc[nt] = (f4v){0.f, 0.f, 0.f, 0.f};
#pragma unroll
    for (int s = 0; s < 4; ++s) {
#pragma unroll
        for (int nt = 0; nt < 8; ++nt) {
            s8v b = *(const s8v*)&BF[(size_t)((s * 8 + nt) * 64 + l) * 8];
            acc[nt] = __builtin_amdgcn_mfma_f32_16x16x32_bf16(af[s].v, b, acc[nt], 0, 0, 0);
        }
        acc[2 * s]     = __builtin_amdgcn_mfma_f32_16x16x32_bf16(xf[s].v, bev.v, acc[2 * s], 0, 0, 0);
        acc[2 * s + 1] = __builtin_amdgcn_mfma_f32_16x16x32_bf16(xf[s].v, bod.v, acc[2 * s + 1], 0, 0, 0);
    }

    // epilogue in C-layout: edge = w*16 + quad*4 + r, col = nt*16 + mrow
    float hsum[4][4];
#pragma unroll
    for (int r = 0; r < 4; ++r)
#pragma unroll
        for (int h = 0; h < 4; ++h) hsum[r][h] = 0.f;
#pragma unroll
    for (int nt = 0; nt < 8; ++nt) {
        int col = nt * 16 + mrow;
        float av = att[col];
        int h = nt >> 1;
#pragma unroll
        for (int r = 0; r < 4; ++r) {
            float m = acc[nt][r];
            float lr = m > 0.f ? m : 0.2f * m;
            hsum[r][h] = fmaf(lr, av, hsum[r][h]);
        }
    }
#pragma unroll
    for (int r = 0; r < 4; ++r)
#pragma unroll
        for (int h = 0; h < 4; ++h) {
            float v = hsum[r][h];
            v += __shfl_xor(v, 1); v += __shfl_xor(v, 2);
            v += __shfl_xor(v, 4); v += __shfl_xor(v, 8);
            hsum[r][h] = v;
        }
    if (mrow == 0) {
#pragma unroll
        for (int r = 0; r < 4; ++r)
#pragma unroll
            for (int h = 0; h < 4; ++h)
                als[w * 16 + quad * 4 + r][h] = hsum[r][h];
    }
    __syncthreads();

    {
        int el = tid >> 2, h = tid & 3;
        g_araw[(size_t)(e0 + el) * H + h] = als[el][h];
    }
}

// ---- fused gather: per-dst softmax (max+denom) + aggregation + bias + act ----
// one wave per dst; block 256 = 4 dsts; grid NN/4
__global__ __launch_bounds__(256) void k_gath(const float* __restrict__ bias,
                                              int do_gelu) {
    const int lane = threadIdx.x & 63;
    const int d = blockIdx.x * 4 + (threadIdx.x >> 6);
    const int off = g_off[d];
    const int deg = g_off[d + 1] - off;
    const int h = lane >> 4;        // head for cols 2*lane, 2*lane+1
    const int slot = lane & 15;

    float mx = -3.4e38f;
    for (int p = slot; p < deg; p += 16)
        mx = fmaxf(mx, g_araw[(size_t)(off + p) * H + h]);
    mx = fmaxf(mx, __shfl_xor(mx, 1));
    mx = fmaxf(mx, __shfl_xor(mx, 2));
    mx = fmaxf(mx, __shfl_xor(mx, 4));
    mx = fmaxf(mx, __shfl_xor(mx, 8));

    float den = 0.f;
    for (int p = slot; p < deg; p += 16)
        den += __expf(g_araw[(size_t)(off + p) * H + h] - mx);
    den += __shfl_xor(den, 1);
    den += __shfl_xor(den, 2);
    den += __shfl_xor(den, 4);
    den += __shfl_xor(den, 8);
    const float inv = 1.f / (den + 1e-16f);

    const int* __restrict__ srcs = g_se + off;
    float a0 = 0.f, a1 = 0.f;
    int p = 0;
    for (; p + 4 <= deg; p += 4) {
        int s0 = srcs[p], s1 = srcs[p + 1], s2 = srcs[p + 2], s3 = srcs[p + 3];
        u32 w0 = *(const u32*)&g_xl[(size_t)s0 * D + lane * 2];
        u32 w1 = *(const u32*)&g_xl[(size_t)s1 * D + lane * 2];
        u32 w2 = *(const u32*)&g_xl[(size_t)s2 * D + lane * 2];
        u32 w3 = *(const u32*)&g_xl[(size_t)s3 * D + lane * 2];
        float c0 = __expf(g_araw[(size_t)(off + p) * H + h] - mx) * inv;
        float c1 = __expf(g_araw[(size_t)(off + p + 1) * H + h] - mx) * inv;
        float c2 = __expf(g_araw[(size_t)(off + p + 2) * H + h] - mx) * inv;
        float c3 = __expf(g_araw[(size_t)(off + p + 3) * H + h] - mx) * inv;
        a0 = fmaf(bflo(w0), c0, a0); a1 = fmaf(bfhi(w0), c0, a1);
        a0 = fmaf(bflo(w1), c1, a0); a1 = fmaf(bfhi(w1), c1, a1);
        a0 = fmaf(bflo(w2), c2, a0); a1 = fmaf(bfhi(w2), c2, a1);
        a0 = fmaf(bflo(w3), c3, a0); a1 = fmaf(bfhi(w3), c3, a1);
    }
    for (; p < deg; ++p) {
        int s = srcs[p];
        float cf = __expf(g_araw[(size_t)(off + p) * H + h] - mx) * inv;
        u32 w = *(const u32*)&g_xl[(size_t)s * D + lane * 2];
        a0 = fmaf(bflo(w), cf, a0);
        a1 = fmaf(bfhi(w), cf, a1);
    }
    float v0 = a0 + bias[lane * 2];
    float v1 = a1 + bias[lane * 2 + 1];
    if (do_gelu) { v0 = gelu_f(v0); v1 = gelu_f(v1); }
    *(float2*)&g_x[(size_t)d * D + lane * 2] = make_float2(v0, v1);
}

// ---- output head (MFMA, LDS-free): y = x[:BS]@out_w + out_b; LayerNorm ----
// grid BS/64, block 256 (4 waves x 16-row tiles)
__global__ __launch_bounds__(256) void k_head(const float* __restrict__ ob,
                                              const float* __restrict__ g,
                                              const float* __restrict__ b,
                                              float* __restrict__ out) {
    const int tid = threadIdx.x;
    const int r0 = blockIdx.x * 64;
    const int l = tid & 63, w = tid >> 6;
    const int mrow = l & 15, quad = l >> 4;
    const float* xrow = g_x + (size_t)(r0 + w * 16 + mrow) * D;
    const u16* BF = g_WnF + (size_t)12 * 2048 * 8;

    f4v acc[8];
#pragma unroll
    for (int nt = 0; nt < 8; ++nt) acc[nt] = (f4v){0.f, 0.f, 0.f, 0.f};
#pragma unroll
    for (int s = 0; s < 4; ++s) {
        int c0 = s * 32 + quad * 8;
        float4 xa = *(const float4*)&xrow[c0];
        float4 xb = *(const float4*)&xrow[c0 + 4];
        union { u32 u[4]; s8v v; } a;
        a.u[0] = pack2r(xa.x, xa.y);
        a.u[1] = pack2r(xa.z, xa.w);
        a.u[2] = pack2r(xb.x, xb.y);
        a.u[3] = pack2r(xb.z, xb.w);
#pragma unroll
        for (int nt = 0; nt < 8; ++nt) {
            s8v bb = *(const s8v*)&BF[(size_t)((s * 8 + nt) * 64 + l) * 8];
            acc[nt] = __builtin_amdgcn_mfma_f32_16x16x32_bf16(a.v, bb, acc[nt], 0, 0, 0);
        }
    }

    // += out_b; per-row (quad*4+r) LayerNorm via 16-lane (mrow) shuffle reduce
    float sum[4] = {0.f, 0.f, 0.f, 0.f};
#pragma unroll
    for (int nt = 0; nt < 8; ++nt) {
        float obv = ob[nt * 16 + mrow];
#pragma unroll
        for (int r = 0; r < 4; ++r) {
            acc[nt][r] += obv;
            sum[r] += acc[nt][r];
        }
    }
    float mu[4];
#pragma unroll
    for (int r = 0; r < 4; ++r) {
        float s = sum[r];
        s += __shfl_xor(s, 1); s += __shfl_xor(s, 2);
        s += __shfl_xor(s, 4); s += __shfl_xor(s, 8);
        mu[r] = s * (1.f / D);
    }
    float sq[4] = {0.f, 0.f, 0.f, 0.f};
#pragma unroll
    for (int nt = 0; nt < 8; ++nt)
#pragma unroll
        for (int r = 0; r < 4; ++r) {
            float dv = acc[nt][r] - mu[r];
            sq[r] += dv * dv;
        }
    float rs[4];
#pragma unroll
    for (int r = 0; r < 4; ++r) {
        float s = sq[r];
        s += __shfl_xor(s, 1); s += __shfl_xor(s, 2);
        s += __shfl_xor(s, 4); s += __shfl_xor(s, 8);
        rs[r] = rsqrtf(s * (1.f / D) + 1e-12f);
    }
#pragma unroll
    for (int nt = 0; nt < 8; ++nt) {
        int col = nt * 16 + mrow;
        float gv = g[col], bv = b[col];
#pragma unroll
        for (int r = 0; r < 4; ++r) {
            int row = r0 + w * 16 + quad * 4 + r;
            out[(size_t)row * D + col] = (acc[nt][r] - mu[r]) * rs[r] * gv + bv;
        }
    }
}

extern "C" void kernel_launch(void* const* d_in, const int* in_sizes, int n_in,
                              void* d_out, int out_size, void* d_ws, size_t ws_size,
                              hipStream_t stream) {
    (void)in_sizes; (void)n_in; (void)out_size; (void)d_ws; (void)ws_size;
    const float* embs = (const float*)d_in[0];
    const int*   ei   = (const int*)d_in[1];
    const int*   et   = (const int*)d_in[2];
    const float* rel  = (const float*)d_in[3];
    const float* wl[2]   = { (const float*)d_in[4],  (const float*)d_in[9]  };
    const float* bl[2]   = { (const float*)d_in[5],  (const float*)d_in[10] };
    const float* we[2]   = { (const float*)d_in[6],  (const float*)d_in[11] };
    const float* attw[2] = { (const float*)d_in[7],  (const float*)d_in[12] };
    const float* bs[2]   = { (const float*)d_in[8],  (const float*)d_in[13] };
    const float* ow  = (const float*)d_in[14];
    const float* ob  = (const float*)d_in[15];
    const float* lng = (const float*)d_in[16];
    const float* lnb = (const float*)d_in[17];
    float* out = (float*)d_out;

    k_cvt<<<NN * D / 256, 256, 0, stream>>>(embs);

    // CSR by dst (edge list shared by both layers)
    k_zcnt<<<NN / 256, 256, 0, stream>>>();
    k_count<<<NE / 256, 256, 0, stream>>>(ei);
    k_scan<<<1, 1024, 0, stream>>>();
    k_scatter<<<NE / 256, 256, 0, stream>>>(ei, et);

    for (int l = 0; l < 2; ++l) {
        const float* Rm = rel + (size_t)l * R * 2 * D * D;
        k_prep<<<dim3(2048 / 256, 13), 256, 0, stream>>>(wl[l], Rm, we[l], ow);
        k_node<<<dim3(NN / 64, 11), 256, 0, stream>>>(bl[l]);
        k_edge<<<NE / 64, 256, 0, stream>>>(attw[l]);
        k_gath<<<NN / 4, 256, 0, stream>>>(bs[l], l == 0 ? 1 : 0);
    }

    k_head<<<BS / 64, 256, 0, stream>>>(ob, lng, lnb, out);
}